// Round 1
// baseline (779.727 us; speedup 1.0000x reference)
//
#include <hip/hip_runtime.h>

#define K49 49

// ============ dense (z @ W + b) + relu -> x0 [2,8,16,1024] ============
__global__ __launch_bounds__(256) void k_dense_relu(
    const float* __restrict__ z, const float* __restrict__ Wd,
    const float* __restrict__ bd, float* __restrict__ x0)
{
    const int D = 131072;
    __shared__ float zs[256];
    const int tid = threadIdx.x;
    zs[tid] = z[tid];                 // z is [2,128] = 256 floats
    __syncthreads();
    const int n = blockIdx.x * 256 + tid;
    const float bb = bd[n];
    float a0 = bb, a1 = bb;
    #pragma unroll 8
    for (int kk = 0; kk < 128; ++kk) {
        const float w = Wd[kk * D + n];
        a0 = fmaf(zs[kk], w, a0);
        a1 = fmaf(zs[128 + kk], w, a1);
    }
    x0[n]     = fmaxf(a0, 0.f);
    x0[D + n] = fmaxf(a1, 0.f);
}

// ============ offset conv as parity-tiled GEMM ============
// The conv input is the zero-stuffed upsample of X[B,H,W,C]; only taps whose
// source coord is (even,even) contribute. For a tile of 16 output pixels of
// the same parity class (rx) in one padded row, the valid tap set is uniform.
// part_off layout: [CG][npix][98]   (npix = pixels in this chunk)
template<int C, int CC>
__global__ __launch_bounds__(64) void k_offgemm(
    const float* __restrict__ X, const int H, const int W,
    const float* __restrict__ OW,      // [7,7,C,98]
    float* __restrict__ part_off,
    const int Hp, const int Wp, const int pix0, const int npix)
{
    const int P = 16;
    const int k  = threadIdx.x;
    const int kc = (k < 48) ? k : 48;      // clamp so idle lanes stay in-bounds
    const int cg = blockIdx.y;
    const int W2  = W / P;                 // 16-pixel tiles per parity-row
    const int TPR = 2 * W2;
    const int r   = blockIdx.x / TPR;
    const int tt  = blockIdx.x - r * TPR;
    const int rx  = tt & 1;
    const int wt  = tt >> 1;
    const int w0  = wt * P;                // base w' (original-grid col)
    const int grow = pix0 / Wp + r;        // global padded row
    const int b    = grow / Hp;
    const int hp   = grow - b * Hp;

    const int ys_lo = (hp - 2) >> 1;       // first source row (may be -1)
    const int NR  = (hp & 1) ? 4 : 3;      // valid row-taps
    const int di0 = (hp & 1) ? 0 : 1;
    const int NC  = rx ? 4 : 3;            // valid col-taps
    const int dj0 = rx ? 0 : 1;

    __shared__ float Xs[4][19][CC];        // [src row][src col - (w0-1)][c]

    const int cbase = cg * CC;
    for (int e = threadIdx.x; e < 4 * 19 * CC; e += 64) {
        const int tr = e / (19 * CC);
        const int rm = e - tr * 19 * CC;
        const int tc = rm / CC;
        const int cc = rm - tc * CC;
        const int ys = ys_lo + tr;
        const int xs = w0 - 1 + tc;
        float v = 0.f;
        if (ys >= 0 && ys < H && xs >= 0 && xs < W)
            v = X[((size_t)((b * H + ys) * W + xs)) * C + cbase + cc];
        Xs[tr][tc][cc] = v;
    }
    __syncthreads();

    float accy[P], accx[P];
    #pragma unroll
    for (int p = 0; p < P; ++p) { accy[p] = 0.f; accx[p] = 0.f; }

    for (int tr = 0; tr < NR; ++tr) {
        const int di = di0 + 2 * tr;
        for (int tcp = 0; tcp < NC; ++tcp) {
            const int dj = dj0 + 2 * tcp;
            const float* owp = OW + ((size_t)((di * 7 + dj) * C + cbase)) * 98 + 2 * kc;
            for (int cc4 = 0; cc4 < CC; cc4 += 4) {
                const float owy0 = owp[(cc4 + 0) * 98], owx0 = owp[(cc4 + 0) * 98 + 1];
                const float owy1 = owp[(cc4 + 1) * 98], owx1 = owp[(cc4 + 1) * 98 + 1];
                const float owy2 = owp[(cc4 + 2) * 98], owx2 = owp[(cc4 + 2) * 98 + 1];
                const float owy3 = owp[(cc4 + 3) * 98], owx3 = owp[(cc4 + 3) * 98 + 1];
                #pragma unroll
                for (int p = 0; p < P; ++p) {
                    const float4 xv = *(const float4*)&Xs[tr][p + tcp][cc4];
                    accy[p] = fmaf(xv.x, owy0, accy[p]);
                    accx[p] = fmaf(xv.x, owx0, accx[p]);
                    accy[p] = fmaf(xv.y, owy1, accy[p]);
                    accx[p] = fmaf(xv.y, owx1, accx[p]);
                    accy[p] = fmaf(xv.z, owy2, accy[p]);
                    accx[p] = fmaf(xv.z, owx2, accx[p]);
                    accy[p] = fmaf(xv.w, owy3, accy[p]);
                    accx[p] = fmaf(xv.w, owx3, accx[p]);
                }
            }
        }
    }

    if (k < 49) {
        #pragma unroll
        for (int p = 0; p < P; ++p) {
            const int wp_p = 2 * (w0 + p) + rx;
            const size_t base = ((size_t)cg * npix + (size_t)r * Wp + wp_p) * 98 + 2 * k;
            part_off[base]     = accy[p];
            part_off[base + 1] = accx[p];
        }
    }
}

// ============ reduce offset partials + compute (s, src) per (pixel, tap) ====
// Exactly one bilinear corner has (even,even) coords -> one gather per tap.
__global__ __launch_bounds__(256) void k_sparams(
    const float* __restrict__ part_off, const float* __restrict__ OB,
    float* __restrict__ SW, int* __restrict__ SIDX,
    const int npix, const int CG,
    const int H, const int W, const int Hp, const int Wp, const int pix0)
{
    const int gid = blockIdx.x * 256 + threadIdx.x;
    if (gid >= npix * K49) return;
    const int pixL = gid / K49;
    const int k = gid - pixL * K49;
    float accy = OB[2 * k], accx = OB[2 * k + 1];
    for (int g = 0; g < CG; ++g) {
        const size_t base = ((size_t)g * npix + pixL) * 98 + 2 * k;
        accy += part_off[base];
        accx += part_off[base + 1];
    }
    const int pixg = pix0 + pixL;
    const int HWp = Hp * Wp;
    const int b = pixg / HWp;
    const int rem = pixg - b * HWp;
    const int hp = rem / Wp;
    const int wp = rem - hp * Wp;

    const float y = (float)(hp + (k / 7) - 3) + accy;
    const float x = (float)(wp + (k % 7) - 3) + accx;
    const float fy0 = floorf(y), fx0 = floorf(x);
    const int iy0 = (int)fy0, ix0 = (int)fx0;
    const float wy1 = y - fy0, wx1 = x - fx0;
    int ye, xe; float wy, wx;
    if (iy0 & 1) { ye = iy0 + 1; wy = wy1; } else { ye = iy0; wy = 1.f - wy1; }
    if (ix0 & 1) { xe = ix0 + 1; wx = wx1; } else { xe = ix0; wx = 1.f - wx1; }
    float s = wy * wx;
    int src = 0;
    if (ye >= 0 && ye < Hp && xe >= 0 && xe < Wp)
        src = (b * H + (ye >> 1)) * W + (xe >> 1);
    else
        s = 0.f;
    SW[gid] = s;
    SIDX[gid] = src;
}

// ============ main deformable conv as split-K GEMM ============
// out[pix,f] = sum_k s_k * sum_c X[src_k, c] * W[k,c,f]
// partial layout: [NKG][npix][F]
template<int C, int F, int KG>
__global__ __launch_bounds__(64) void k_dconv(
    const float* __restrict__ X, const float* __restrict__ Wt,  // Wt: [49,C,F]
    const float* __restrict__ SW, const int* __restrict__ SIDX,
    float* __restrict__ partial, const int npix)
{
    constexpr int TILE_M = 32;
    constexpr int TN = 4;
    constexpr int NF = F / TN;      // f-groups: 16 / 8 / 4
    constexpr int MG = 64 / NF;     // m-groups: 4 / 8 / 16
    constexpr int TM = TILE_M / MG; // 8 / 4 / 2
    constexpr int CC = 32;

    __shared__ float Xst[TILE_M][CC + 1];
    __shared__ float Wsh[CC * F];
    __shared__ float Ss[TILE_M];
    __shared__ int   Is[TILE_M];

    const int tid = threadIdx.x;
    const int fg = tid % NF, mg = tid / NF;
    const int f0 = fg * TN, m0 = mg * TM;
    const int pixb = blockIdx.x * TILE_M;
    const int kg = blockIdx.y;

    float acc[TM][TN];
    #pragma unroll
    for (int j = 0; j < TM; ++j)
        #pragma unroll
        for (int i = 0; i < TN; ++i) acc[j][i] = 0.f;

    for (int kk = 0; kk < KG; ++kk) {
        const int k = kg * KG + kk;
        if (k >= 49) break;
        if (tid < TILE_M) {
            Ss[tid] = SW[(size_t)(pixb + tid) * K49 + k];
            Is[tid] = SIDX[(size_t)(pixb + tid) * K49 + k];
        }
        __syncthreads();
        for (int c0 = 0; c0 < C; c0 += CC) {
            for (int t = tid; t < TILE_M * CC; t += 64) {
                const int m = t / CC;
                const int cc = t - m * CC;
                Xst[m][cc] = Ss[m] * X[(size_t)Is[m] * C + c0 + cc];
            }
            const float* wg = Wt + ((size_t)k * C + c0) * F;
            for (int t = tid; t < CC * F; t += 64) Wsh[t] = wg[t];
            __syncthreads();
            #pragma unroll
            for (int cc = 0; cc < CC; ++cc) {
                float xv[TM], wv[TN];
                #pragma unroll
                for (int j = 0; j < TM; ++j) xv[j] = Xst[m0 + j][cc];
                #pragma unroll
                for (int i = 0; i < TN; ++i) wv[i] = Wsh[cc * F + f0 + i];
                #pragma unroll
                for (int j = 0; j < TM; ++j)
                    #pragma unroll
                    for (int i = 0; i < TN; ++i)
                        acc[j][i] = fmaf(xv[j], wv[i], acc[j][i]);
            }
            __syncthreads();
        }
    }
    #pragma unroll
    for (int j = 0; j < TM; ++j) {
        const int pix = pixb + m0 + j;
        #pragma unroll
        for (int i = 0; i < TN; ++i)
            partial[((size_t)kg * npix + pix) * F + f0 + i] = acc[j][i];
    }
}

// ============ reduce split-K partials + bias (+relu) ============
__global__ __launch_bounds__(256) void k_reduce(
    const float* __restrict__ partial, const float* __restrict__ bias,
    float* __restrict__ out, const int npix, const int F, const int NKG,
    const int do_relu)
{
    const int gid = blockIdx.x * 256 + threadIdx.x;
    if (gid >= npix * F) return;
    const int f = gid % F;
    float acc = bias[f];
    const size_t stride = (size_t)npix * F;
    for (int g = 0; g < NKG; ++g) acc += partial[(size_t)g * stride + gid];
    out[gid] = do_relu ? fmaxf(acc, 0.f) : acc;
}

// ============ stage 4: F=1, thread-per-pixel ============
__global__ __launch_bounds__(256) void k_dconv_f1(
    const float* __restrict__ X,        // [2*64*128, 16]
    const float* __restrict__ Wt,       // [49*16]
    const float* __restrict__ SW, const int* __restrict__ SIDX,
    const float* __restrict__ bias, float* __restrict__ out,
    const int pix0, const int npix)
{
    const int gid = blockIdx.x * 256 + threadIdx.x;
    if (gid >= npix) return;
    float acc = 0.f;
    for (int k = 0; k < 49; ++k) {
        const float s = SW[(size_t)gid * K49 + k];
        const int src = SIDX[(size_t)gid * K49 + k];
        const float4* xr = (const float4*)(X + (size_t)src * 16);
        const float4* wr = (const float4*)(Wt + k * 16);
        float4 a, w4;
        float d = 0.f;
        a = xr[0]; w4 = wr[0]; d += a.x*w4.x + a.y*w4.y + a.z*w4.z + a.w*w4.w;
        a = xr[1]; w4 = wr[1]; d += a.x*w4.x + a.y*w4.y + a.z*w4.z + a.w*w4.w;
        a = xr[2]; w4 = wr[2]; d += a.x*w4.x + a.y*w4.y + a.z*w4.z + a.w*w4.w;
        a = xr[3]; w4 = wr[3]; d += a.x*w4.x + a.y*w4.y + a.z*w4.z + a.w*w4.w;
        acc = fmaf(s, d, acc);
    }
    out[pix0 + gid] = acc + bias[0];
}

extern "C" void kernel_launch(void* const* d_in, const int* in_sizes, int n_in,
                              void* d_out, int out_size, void* d_ws, size_t ws_size,
                              hipStream_t stream) {
    const float* z   = (const float*)d_in[0];
    const float* dw  = (const float*)d_in[1];
    const float* db  = (const float*)d_in[2];
    const float* ow1 = (const float*)d_in[3];
    const float* ob1 = (const float*)d_in[4];
    const float* w1  = (const float*)d_in[5];
    const float* b1  = (const float*)d_in[6];
    const float* ow2 = (const float*)d_in[7];
    const float* ob2 = (const float*)d_in[8];
    const float* w2  = (const float*)d_in[9];
    const float* b2  = (const float*)d_in[10];
    const float* ow3 = (const float*)d_in[11];
    const float* ob3 = (const float*)d_in[12];
    const float* w3  = (const float*)d_in[13];
    const float* b3  = (const float*)d_in[14];
    const float* ow4 = (const float*)d_in[15];
    const float* ob4 = (const float*)d_in[16];
    const float* w4  = (const float*)d_in[17];
    const float* b4  = (const float*)d_in[18];

    // workspace layout (floats): total 5,734,400 floats = 22.9 MB
    float* ws   = (float*)d_ws;
    float* x0   = ws;                    // 262144  [2,8,16,1024]
    float* x1   = x0 + 262144;           // 65536   [2,16,32,64]
    float* x2   = x1 + 65536;            // 131072  [2,32,64,32]
    float* x3   = x2 + 131072;           // 262144  [2,64,128,16]
    float* sw   = x3 + 262144;           // 802816  (16384 pix * 49)
    int*   sidx = (int*)(sw + 802816);   // 802816
    float* part = (float*)(sidx + 802816); // 3407872 (shared: off-partials & K-partials)

    float* out = (float*)d_out;

    // ---- dense + relu ----
    k_dense_relu<<<512, 256, 0, stream>>>(z, dw, db, x0);

    // ---- stage 1: x0 [2,8,16,1024] -> x1 [2,16,32,64] ----
    {
        const int H = 8, W = 16, Hp = 16, Wp = 32, npix = 1024, CG = 32;
        dim3 go((npix / Wp) * 2 * (W / 16), CG);
        k_offgemm<1024, 32><<<go, 64, 0, stream>>>(x0, H, W, ow1, part, Hp, Wp, 0, npix);
        k_sparams<<<(npix * K49 + 255) / 256, 256, 0, stream>>>(part, ob1, sw, sidx, npix, CG, H, W, Hp, Wp, 0);
        dim3 gd(npix / 32, 49);
        k_dconv<1024, 64, 1><<<gd, 64, 0, stream>>>(x0, w1, sw, sidx, part, npix);
        k_reduce<<<(npix * 64 + 255) / 256, 256, 0, stream>>>(part, b1, x1, npix, 64, 49, 1);
    }

    // ---- stage 2: x1 [2,16,32,64] -> x2 [2,32,64,32] ----
    {
        const int H = 16, W = 32, Hp = 32, Wp = 64, npix = 4096, CG = 2;
        dim3 go((npix / Wp) * 2 * (W / 16), CG);
        k_offgemm<64, 32><<<go, 64, 0, stream>>>(x1, H, W, ow2, part, Hp, Wp, 0, npix);
        k_sparams<<<(npix * K49 + 255) / 256, 256, 0, stream>>>(part, ob2, sw, sidx, npix, CG, H, W, Hp, Wp, 0);
        dim3 gd(npix / 32, 13);
        k_dconv<64, 32, 4><<<gd, 64, 0, stream>>>(x1, w2, sw, sidx, part, npix);
        k_reduce<<<(npix * 32 + 255) / 256, 256, 0, stream>>>(part, b2, x2, npix, 32, 13, 1);
    }

    // ---- stage 3: x2 [2,32,64,32] -> x3 [2,64,128,16] ----
    {
        const int H = 32, W = 64, Hp = 64, Wp = 128, npix = 16384, CG = 1;
        dim3 go((npix / Wp) * 2 * (W / 16), CG);
        k_offgemm<32, 32><<<go, 64, 0, stream>>>(x2, H, W, ow3, part, Hp, Wp, 0, npix);
        k_sparams<<<(npix * K49 + 255) / 256, 256, 0, stream>>>(part, ob3, sw, sidx, npix, CG, H, W, Hp, Wp, 0);
        dim3 gd(npix / 32, 13);
        k_dconv<32, 16, 4><<<gd, 64, 0, stream>>>(x2, w3, sw, sidx, part, npix);
        k_reduce<<<(npix * 16 + 255) / 256, 256, 0, stream>>>(part, b3, x3, npix, 16, 13, 1);
    }

    // ---- stage 4: x3 [2,64,128,16] -> out [2,128,256,1], 4 chunks ----
    {
        const int H = 64, W = 128, Hp = 128, Wp = 256, CHUNK = 16384, CG = 1;
        for (int c = 0; c < 4; ++c) {
            const int pix0 = c * CHUNK;
            dim3 go((CHUNK / Wp) * 2 * (W / 16), CG);
            k_offgemm<16, 16><<<go, 64, 0, stream>>>(x3, H, W, ow4, part, Hp, Wp, pix0, CHUNK);
            k_sparams<<<(CHUNK * K49 + 255) / 256, 256, 0, stream>>>(part, ob4, sw, sidx, CHUNK, CG, H, W, Hp, Wp, pix0);
            k_dconv_f1<<<CHUNK / 256, 256, 0, stream>>>(x3, w4, sw, sidx, b4, out, pix0, CHUNK);
        }
    }
}

// Round 2
// 595.057 us; speedup vs baseline: 1.3103x; 1.3103x over previous
//
#include <hip/hip_runtime.h>

#define K49 49

// ============ dense (z @ W + b) + relu -> x0 [2,8,16,1024] ============
__global__ __launch_bounds__(256) void k_dense_relu(
    const float* __restrict__ z, const float* __restrict__ Wd,
    const float* __restrict__ bd, float* __restrict__ x0)
{
    const int D = 131072;
    __shared__ float zs[256];
    const int tid = threadIdx.x;
    zs[tid] = z[tid];                 // z is [2,128] = 256 floats
    __syncthreads();
    const int n = blockIdx.x * 256 + tid;
    const float bb = bd[n];
    float a0 = bb, a1 = bb;
    #pragma unroll 8
    for (int kk = 0; kk < 128; ++kk) {
        const float w = Wd[kk * D + n];
        a0 = fmaf(zs[kk], w, a0);
        a1 = fmaf(zs[128 + kk], w, a1);
    }
    x0[n]     = fmaxf(a0, 0.f);
    x0[D + n] = fmaxf(a1, 0.f);
}

// ============ offset conv as parity-tiled GEMM ============
// part_off layout: [CG][npix][98]
template<int C, int CC>
__global__ __launch_bounds__(64) void k_offgemm(
    const float* __restrict__ X, const int H, const int W,
    const float* __restrict__ OW,      // [7,7,C,98]
    float* __restrict__ part_off,
    const int Hp, const int Wp, const int pix0, const int npix)
{
    const int P = 16;
    const int k  = threadIdx.x;
    const int kc = (k < 48) ? k : 48;
    const int cg = blockIdx.y;
    const int W2  = W / P;
    const int TPR = 2 * W2;
    const int r   = blockIdx.x / TPR;
    const int tt  = blockIdx.x - r * TPR;
    const int rx  = tt & 1;
    const int wt  = tt >> 1;
    const int w0  = wt * P;
    const int grow = pix0 / Wp + r;
    const int b    = grow / Hp;
    const int hp   = grow - b * Hp;

    const int ys_lo = (hp - 2) >> 1;
    const int NR  = (hp & 1) ? 4 : 3;
    const int di0 = (hp & 1) ? 0 : 1;
    const int NC  = rx ? 4 : 3;
    const int dj0 = rx ? 0 : 1;

    __shared__ float Xs[4][19][CC];

    const int cbase = cg * CC;
    for (int e = threadIdx.x; e < 4 * 19 * CC; e += 64) {
        const int tr = e / (19 * CC);
        const int rm = e - tr * 19 * CC;
        const int tc = rm / CC;
        const int cc = rm - tc * CC;
        const int ys = ys_lo + tr;
        const int xs = w0 - 1 + tc;
        float v = 0.f;
        if (ys >= 0 && ys < H && xs >= 0 && xs < W)
            v = X[((size_t)((b * H + ys) * W + xs)) * C + cbase + cc];
        Xs[tr][tc][cc] = v;
    }
    __syncthreads();

    float accy[P], accx[P];
    #pragma unroll
    for (int p = 0; p < P; ++p) { accy[p] = 0.f; accx[p] = 0.f; }

    for (int tr = 0; tr < NR; ++tr) {
        const int di = di0 + 2 * tr;
        for (int tcp = 0; tcp < NC; ++tcp) {
            const int dj = dj0 + 2 * tcp;
            const float* owp = OW + ((size_t)((di * 7 + dj) * C + cbase)) * 98 + 2 * kc;
            for (int cc4 = 0; cc4 < CC; cc4 += 4) {
                const float owy0 = owp[(cc4 + 0) * 98], owx0 = owp[(cc4 + 0) * 98 + 1];
                const float owy1 = owp[(cc4 + 1) * 98], owx1 = owp[(cc4 + 1) * 98 + 1];
                const float owy2 = owp[(cc4 + 2) * 98], owx2 = owp[(cc4 + 2) * 98 + 1];
                const float owy3 = owp[(cc4 + 3) * 98], owx3 = owp[(cc4 + 3) * 98 + 1];
                #pragma unroll
                for (int p = 0; p < P; ++p) {
                    const float4 xv = *(const float4*)&Xs[tr][p + tcp][cc4];
                    accy[p] = fmaf(xv.x, owy0, accy[p]);
                    accx[p] = fmaf(xv.x, owx0, accx[p]);
                    accy[p] = fmaf(xv.y, owy1, accy[p]);
                    accx[p] = fmaf(xv.y, owx1, accx[p]);
                    accy[p] = fmaf(xv.z, owy2, accy[p]);
                    accx[p] = fmaf(xv.z, owx2, accx[p]);
                    accy[p] = fmaf(xv.w, owy3, accy[p]);
                    accx[p] = fmaf(xv.w, owx3, accx[p]);
                }
            }
        }
    }

    if (k < 49) {
        #pragma unroll
        for (int p = 0; p < P; ++p) {
            const int wp_p = 2 * (w0 + p) + rx;
            const size_t base = ((size_t)cg * npix + (size_t)r * Wp + wp_p) * 98 + 2 * k;
            part_off[base]     = accy[p];
            part_off[base + 1] = accx[p];
        }
    }
}

// ============ reduce offset partials + compute (s, src) per (pixel, tap) ====
__global__ __launch_bounds__(256) void k_sparams(
    const float* __restrict__ part_off, const float* __restrict__ OB,
    float* __restrict__ SW, int* __restrict__ SIDX,
    const int npix, const int CG,
    const int H, const int W, const int Hp, const int Wp, const int pix0)
{
    const int gid = blockIdx.x * 256 + threadIdx.x;
    if (gid >= npix * K49) return;
    const int pixL = gid / K49;
    const int k = gid - pixL * K49;
    float accy = OB[2 * k], accx = OB[2 * k + 1];
    for (int g = 0; g < CG; ++g) {
        const size_t base = ((size_t)g * npix + pixL) * 98 + 2 * k;
        accy += part_off[base];
        accx += part_off[base + 1];
    }
    const int pixg = pix0 + pixL;
    const int HWp = Hp * Wp;
    const int b = pixg / HWp;
    const int rem = pixg - b * HWp;
    const int hp = rem / Wp;
    const int wp = rem - hp * Wp;

    const float y = (float)(hp + (k / 7) - 3) + accy;
    const float x = (float)(wp + (k % 7) - 3) + accx;
    const float fy0 = floorf(y), fx0 = floorf(x);
    const int iy0 = (int)fy0, ix0 = (int)fx0;
    const float wy1 = y - fy0, wx1 = x - fx0;
    int ye, xe; float wy, wx;
    if (iy0 & 1) { ye = iy0 + 1; wy = wy1; } else { ye = iy0; wy = 1.f - wy1; }
    if (ix0 & 1) { xe = ix0 + 1; wx = wx1; } else { xe = ix0; wx = 1.f - wx1; }
    float s = wy * wx;
    int src = 0;
    if (ye >= 0 && ye < Hp && xe >= 0 && xe < Wp)
        src = (b * H + (ye >> 1)) * W + (xe >> 1);
    else
        s = 0.f;
    SW[gid] = s;
    SIDX[gid] = src;
}

// ============ main deformable conv: 256-thread register-tiled GEMM ============
// out[pix,f] = sum_k s_k * sum_c X[src_k, c] * W[k,c,f]
// partial layout: [NKG][npix][F].  Thread tile 4m x 4f, M-tile = 4096/F.
template<int C, int F, int KG>
__global__ __launch_bounds__(256) void k_dconv(
    const float* __restrict__ X, const float* __restrict__ Wt,  // Wt: [49,C,F]
    const float* __restrict__ SW, const int* __restrict__ SIDX,
    float* __restrict__ partial, const int npix)
{
    constexpr int TILE_M = 4096 / F;     // 64 / 128 / 256
    constexpr int CC = 32;
    constexpr int NF = F / 4;            // f-groups: 16 / 8 / 4
    constexpr int MG = 256 / NF;         // 16 / 32 / 64
    static_assert(TILE_M == MG * 4, "tile mismatch");
    constexpr int LDM = TILE_M + 4;      // pad keeps float4 alignment

    __shared__ float Xst[CC][LDM];       // c-major: float4 reads over m
    __shared__ float Wsh[CC][F];
    __shared__ float Ss[TILE_M];
    __shared__ int   Is[TILE_M];

    const int tid = threadIdx.x;
    const int fg = tid % NF, mg = tid / NF;
    const int f0 = fg * 4, m0 = mg * 4;
    const int pixb = blockIdx.x * TILE_M;
    const int kg = blockIdx.y;

    float acc[4][4];
    #pragma unroll
    for (int j = 0; j < 4; ++j)
        #pragma unroll
        for (int i = 0; i < 4; ++i) acc[j][i] = 0.f;

    for (int kk = 0; kk < KG; ++kk) {
        const int k = kg * KG + kk;
        if (k >= 49) break;
        __syncthreads();   // protect Ss/Is from previous iter readers
        if (tid < TILE_M) {
            Ss[tid] = SW[(size_t)(pixb + tid) * K49 + k];
            Is[tid] = SIDX[(size_t)(pixb + tid) * K49 + k];
        }
        __syncthreads();
        for (int c0 = 0; c0 < C; c0 += CC) {
            // stage X gather (scaled) transposed into Xst
            for (int e = tid; e < TILE_M * 8; e += 256) {
                const int m = e >> 3, c4 = (e & 7) << 2;
                const float4 v = *(const float4*)&X[(size_t)Is[m] * C + c0 + c4];
                const float s = Ss[m];
                Xst[c4 + 0][m] = s * v.x;
                Xst[c4 + 1][m] = s * v.y;
                Xst[c4 + 2][m] = s * v.z;
                Xst[c4 + 3][m] = s * v.w;
            }
            // stage weights
            const float* wg = Wt + ((size_t)k * C + c0) * F;
            for (int t = tid; t < CC * F / 4; t += 256)
                ((float4*)Wsh)[t] = ((const float4*)wg)[t];
            __syncthreads();
            #pragma unroll
            for (int cc = 0; cc < CC; ++cc) {
                const float4 xv = *(const float4*)&Xst[cc][m0];
                const float4 wv = *(const float4*)&Wsh[cc][f0];
                acc[0][0] = fmaf(xv.x, wv.x, acc[0][0]);
                acc[0][1] = fmaf(xv.x, wv.y, acc[0][1]);
                acc[0][2] = fmaf(xv.x, wv.z, acc[0][2]);
                acc[0][3] = fmaf(xv.x, wv.w, acc[0][3]);
                acc[1][0] = fmaf(xv.y, wv.x, acc[1][0]);
                acc[1][1] = fmaf(xv.y, wv.y, acc[1][1]);
                acc[1][2] = fmaf(xv.y, wv.z, acc[1][2]);
                acc[1][3] = fmaf(xv.y, wv.w, acc[1][3]);
                acc[2][0] = fmaf(xv.z, wv.x, acc[2][0]);
                acc[2][1] = fmaf(xv.z, wv.y, acc[2][1]);
                acc[2][2] = fmaf(xv.z, wv.z, acc[2][2]);
                acc[2][3] = fmaf(xv.z, wv.w, acc[2][3]);
                acc[3][0] = fmaf(xv.w, wv.x, acc[3][0]);
                acc[3][1] = fmaf(xv.w, wv.y, acc[3][1]);
                acc[3][2] = fmaf(xv.w, wv.z, acc[3][2]);
                acc[3][3] = fmaf(xv.w, wv.w, acc[3][3]);
            }
            __syncthreads();
        }
    }
    #pragma unroll
    for (int j = 0; j < 4; ++j) {
        const int pix = pixb + m0 + j;
        float4 o = make_float4(acc[j][0], acc[j][1], acc[j][2], acc[j][3]);
        *(float4*)&partial[((size_t)kg * npix + pix) * F + f0] = o;
    }
}

// ============ reduce split-K partials + bias (+relu) ============
__global__ __launch_bounds__(256) void k_reduce(
    const float* __restrict__ partial, const float* __restrict__ bias,
    float* __restrict__ out, const int npix, const int F, const int NKG,
    const int do_relu)
{
    const int gid = blockIdx.x * 256 + threadIdx.x;
    if (gid >= npix * F) return;
    const int f = gid % F;
    float acc = bias[f];
    const size_t stride = (size_t)npix * F;
    for (int g = 0; g < NKG; ++g) acc += partial[(size_t)g * stride + gid];
    out[gid] = do_relu ? fmaxf(acc, 0.f) : acc;
}

// ============ stage 4: F=1, fused sparams, 4-lane tap split ============
__global__ __launch_bounds__(256) void k_dconv_f1(
    const float* __restrict__ X,        // [2*64*128, 16]
    const float* __restrict__ Wt,       // [49*16]
    const float* __restrict__ part,     // [npix, 98] raw offset conv (no bias)
    const float* __restrict__ OB,       // [98]
    const float* __restrict__ bias, float* __restrict__ out,
    const int H, const int W, const int Hp, const int Wp,
    const int pix0, const int npix)
{
    __shared__ float Wsh[49 * 16];
    __shared__ float OBs[98];
    const int tid = threadIdx.x;
    for (int t = tid; t < 49 * 16; t += 256) Wsh[t] = Wt[t];
    if (tid < 98) OBs[tid] = OB[tid];
    __syncthreads();

    const int pixL = blockIdx.x * 64 + (tid >> 2);
    const int tq = tid & 3;
    const int t0 = (tq == 0) ? 0 : 13 + (tq - 1) * 12;
    const int t1 = t0 + ((tq == 0) ? 13 : 12);

    const int pixg = pix0 + pixL;
    const int HWp = Hp * Wp;
    const int b = pixg / HWp;
    const int rem = pixg - b * HWp;
    const int hp = rem / Wp;
    const int wp = rem - hp * Wp;

    float acc = 0.f;
    for (int k = t0; k < t1; ++k) {
        const float offy = part[(size_t)pixL * 98 + 2 * k]     + OBs[2 * k];
        const float offx = part[(size_t)pixL * 98 + 2 * k + 1] + OBs[2 * k + 1];
        const float y = (float)(hp + (k / 7) - 3) + offy;
        const float x = (float)(wp + (k % 7) - 3) + offx;
        const float fy0 = floorf(y), fx0 = floorf(x);
        const int iy0 = (int)fy0, ix0 = (int)fx0;
        const float wy1 = y - fy0, wx1 = x - fx0;
        int ye, xe; float wy, wx;
        if (iy0 & 1) { ye = iy0 + 1; wy = wy1; } else { ye = iy0; wy = 1.f - wy1; }
        if (ix0 & 1) { xe = ix0 + 1; wx = wx1; } else { xe = ix0; wx = 1.f - wx1; }
        float s = wy * wx;
        int src = 0;
        if (ye >= 0 && ye < Hp && xe >= 0 && xe < Wp)
            src = (b * H + (ye >> 1)) * W + (xe >> 1);
        else
            s = 0.f;
        const float4* xr = (const float4*)(X + (size_t)src * 16);
        const float*  wr = Wsh + k * 16;
        float d = 0.f;
        float4 a;
        a = xr[0]; d += a.x*wr[0]  + a.y*wr[1]  + a.z*wr[2]  + a.w*wr[3];
        a = xr[1]; d += a.x*wr[4]  + a.y*wr[5]  + a.z*wr[6]  + a.w*wr[7];
        a = xr[2]; d += a.x*wr[8]  + a.y*wr[9]  + a.z*wr[10] + a.w*wr[11];
        a = xr[3]; d += a.x*wr[12] + a.y*wr[13] + a.z*wr[14] + a.w*wr[15];
        acc = fmaf(s, d, acc);
    }
    acc += __shfl_xor(acc, 1);
    acc += __shfl_xor(acc, 2);
    if (tq == 0) out[pixg] = acc + bias[0];
}

extern "C" void kernel_launch(void* const* d_in, const int* in_sizes, int n_in,
                              void* d_out, int out_size, void* d_ws, size_t ws_size,
                              hipStream_t stream) {
    const float* z   = (const float*)d_in[0];
    const float* dw  = (const float*)d_in[1];
    const float* db  = (const float*)d_in[2];
    const float* ow1 = (const float*)d_in[3];
    const float* ob1 = (const float*)d_in[4];
    const float* w1  = (const float*)d_in[5];
    const float* b1  = (const float*)d_in[6];
    const float* ow2 = (const float*)d_in[7];
    const float* ob2 = (const float*)d_in[8];
    const float* w2  = (const float*)d_in[9];
    const float* b2  = (const float*)d_in[10];
    const float* ow3 = (const float*)d_in[11];
    const float* ob3 = (const float*)d_in[12];
    const float* w3  = (const float*)d_in[13];
    const float* b3  = (const float*)d_in[14];
    const float* ow4 = (const float*)d_in[15];
    const float* ob4 = (const float*)d_in[16];
    const float* w4  = (const float*)d_in[17];
    const float* b4  = (const float*)d_in[18];

    // workspace layout (floats): total 5,734,400 floats = 22.9 MB
    float* ws   = (float*)d_ws;
    float* x0   = ws;                    // 262144  [2,8,16,1024]
    float* x1   = x0 + 262144;           // 65536   [2,16,32,64]
    float* x2   = x1 + 65536;            // 131072  [2,32,64,32]
    float* x3   = x2 + 131072;           // 262144  [2,64,128,16]
    float* sw   = x3 + 262144;           // 802816  (16384 pix * 49)
    int*   sidx = (int*)(sw + 802816);   // 802816
    float* part = (float*)(sidx + 802816); // 3407872 (shared: off-partials & K-partials)

    float* out = (float*)d_out;

    // ---- dense + relu ----
    k_dense_relu<<<512, 256, 0, stream>>>(z, dw, db, x0);

    // ---- stage 1: x0 [2,8,16,1024] -> x1 [2,16,32,64] ----
    {
        const int H = 8, W = 16, Hp = 16, Wp = 32, npix = 1024, CG = 32;
        dim3 go((npix / Wp) * 2 * (W / 16), CG);
        k_offgemm<1024, 32><<<go, 64, 0, stream>>>(x0, H, W, ow1, part, Hp, Wp, 0, npix);
        k_sparams<<<(npix * K49 + 255) / 256, 256, 0, stream>>>(part, ob1, sw, sidx, npix, CG, H, W, Hp, Wp, 0);
        dim3 gd(npix / 64, 49);
        k_dconv<1024, 64, 1><<<gd, 256, 0, stream>>>(x0, w1, sw, sidx, part, npix);
        k_reduce<<<(npix * 64 + 255) / 256, 256, 0, stream>>>(part, b1, x1, npix, 64, 49, 1);
    }

    // ---- stage 2: x1 [2,16,32,64] -> x2 [2,32,64,32] ----
    {
        const int H = 16, W = 32, Hp = 32, Wp = 64, npix = 4096, CG = 2;
        dim3 go((npix / Wp) * 2 * (W / 16), CG);
        k_offgemm<64, 32><<<go, 64, 0, stream>>>(x1, H, W, ow2, part, Hp, Wp, 0, npix);
        k_sparams<<<(npix * K49 + 255) / 256, 256, 0, stream>>>(part, ob2, sw, sidx, npix, CG, H, W, Hp, Wp, 0);
        dim3 gd(npix / 128, 25);
        k_dconv<64, 32, 2><<<gd, 256, 0, stream>>>(x1, w2, sw, sidx, part, npix);
        k_reduce<<<(npix * 32 + 255) / 256, 256, 0, stream>>>(part, b2, x2, npix, 32, 25, 1);
    }

    // ---- stage 3: x2 [2,32,64,32] -> x3 [2,64,128,16] ----
    {
        const int H = 32, W = 64, Hp = 64, Wp = 128, npix = 16384, CG = 1;
        dim3 go((npix / Wp) * 2 * (W / 16), CG);
        k_offgemm<32, 32><<<go, 64, 0, stream>>>(x2, H, W, ow3, part, Hp, Wp, 0, npix);
        k_sparams<<<(npix * K49 + 255) / 256, 256, 0, stream>>>(part, ob3, sw, sidx, npix, CG, H, W, Hp, Wp, 0);
        dim3 gd(npix / 256, 13);
        k_dconv<32, 16, 4><<<gd, 256, 0, stream>>>(x2, w3, sw, sidx, part, npix);
        k_reduce<<<(npix * 16 + 255) / 256, 256, 0, stream>>>(part, b3, x3, npix, 16, 13, 1);
    }

    // ---- stage 4: x3 [2,64,128,16] -> out [2,128,256,1], 4 chunks ----
    {
        const int H = 64, W = 128, Hp = 128, Wp = 256, CHUNK = 16384;
        for (int c = 0; c < 4; ++c) {
            const int pix0 = c * CHUNK;
            dim3 go((CHUNK / Wp) * 2 * (W / 16), 1);
            k_offgemm<16, 16><<<go, 64, 0, stream>>>(x3, H, W, ow4, part, Hp, Wp, pix0, CHUNK);
            k_dconv_f1<<<CHUNK / 64, 256, 0, stream>>>(x3, w4, part, ob4, b4, out, H, W, Hp, Wp, pix0, CHUNK);
        }
    }
}

// Round 3
// 484.261 us; speedup vs baseline: 1.6101x; 1.2288x over previous
//
#include <hip/hip_runtime.h>

#define K49 49

// ============ dense (z @ W + b) + relu -> x0 [2,8,16,1024] ============
__global__ __launch_bounds__(256) void k_dense_relu(
    const float* __restrict__ z, const float* __restrict__ Wd,
    const float* __restrict__ bd, float* __restrict__ x0)
{
    const int D = 131072;
    __shared__ float zs[256];
    const int tid = threadIdx.x;
    zs[tid] = z[tid];                 // z is [2,128] = 256 floats
    __syncthreads();
    const int n = blockIdx.x * 256 + tid;
    const float bb = bd[n];
    float a0 = bb, a1 = bb;
    #pragma unroll 8
    for (int kk = 0; kk < 128; ++kk) {
        const float w = Wd[kk * D + n];
        a0 = fmaf(zs[kk], w, a0);
        a1 = fmaf(zs[128 + kk], w, a1);
    }
    x0[n]     = fmaxf(a0, 0.f);
    x0[D + n] = fmaxf(a1, 0.f);
}

// ============ offset conv as parity-tiled GEMM ============
// part_off layout: [CG][npix][98]
template<int C, int CC>
__global__ __launch_bounds__(64) void k_offgemm(
    const float* __restrict__ X, const int H, const int W,
    const float* __restrict__ OW,      // [7,7,C,98]
    float* __restrict__ part_off,
    const int Hp, const int Wp, const int pix0, const int npix)
{
    const int P = 16;
    const int k  = threadIdx.x;
    const int kc = (k < 48) ? k : 48;
    const int cg = blockIdx.y;
    const int W2  = W / P;
    const int TPR = 2 * W2;
    const int r   = blockIdx.x / TPR;
    const int tt  = blockIdx.x - r * TPR;
    const int rx  = tt & 1;
    const int wt  = tt >> 1;
    const int w0  = wt * P;
    const int grow = pix0 / Wp + r;
    const int b    = grow / Hp;
    const int hp   = grow - b * Hp;

    const int ys_lo = (hp - 2) >> 1;
    const int NR  = (hp & 1) ? 4 : 3;
    const int di0 = (hp & 1) ? 0 : 1;
    const int NC  = rx ? 4 : 3;
    const int dj0 = rx ? 0 : 1;

    __shared__ float Xs[4][19][CC];

    const int cbase = cg * CC;
    for (int e = threadIdx.x; e < 4 * 19 * CC; e += 64) {
        const int tr = e / (19 * CC);
        const int rm = e - tr * 19 * CC;
        const int tc = rm / CC;
        const int cc = rm - tc * CC;
        const int ys = ys_lo + tr;
        const int xs = w0 - 1 + tc;
        float v = 0.f;
        if (ys >= 0 && ys < H && xs >= 0 && xs < W)
            v = X[((size_t)((b * H + ys) * W + xs)) * C + cbase + cc];
        Xs[tr][tc][cc] = v;
    }
    __syncthreads();

    float accy[P], accx[P];
    #pragma unroll
    for (int p = 0; p < P; ++p) { accy[p] = 0.f; accx[p] = 0.f; }

    for (int tr = 0; tr < NR; ++tr) {
        const int di = di0 + 2 * tr;
        for (int tcp = 0; tcp < NC; ++tcp) {
            const int dj = dj0 + 2 * tcp;
            const float* owp = OW + ((size_t)((di * 7 + dj) * C + cbase)) * 98 + 2 * kc;
            for (int cc4 = 0; cc4 < CC; cc4 += 4) {
                const float owy0 = owp[(cc4 + 0) * 98], owx0 = owp[(cc4 + 0) * 98 + 1];
                const float owy1 = owp[(cc4 + 1) * 98], owx1 = owp[(cc4 + 1) * 98 + 1];
                const float owy2 = owp[(cc4 + 2) * 98], owx2 = owp[(cc4 + 2) * 98 + 1];
                const float owy3 = owp[(cc4 + 3) * 98], owx3 = owp[(cc4 + 3) * 98 + 1];
                #pragma unroll
                for (int p = 0; p < P; ++p) {
                    const float4 xv = *(const float4*)&Xs[tr][p + tcp][cc4];
                    accy[p] = fmaf(xv.x, owy0, accy[p]);
                    accx[p] = fmaf(xv.x, owx0, accx[p]);
                    accy[p] = fmaf(xv.y, owy1, accy[p]);
                    accx[p] = fmaf(xv.y, owx1, accx[p]);
                    accy[p] = fmaf(xv.z, owy2, accy[p]);
                    accx[p] = fmaf(xv.z, owx2, accx[p]);
                    accy[p] = fmaf(xv.w, owy3, accy[p]);
                    accx[p] = fmaf(xv.w, owx3, accx[p]);
                }
            }
        }
    }

    if (k < 49) {
        #pragma unroll
        for (int p = 0; p < P; ++p) {
            const int wp_p = 2 * (w0 + p) + rx;
            const size_t base = ((size_t)cg * npix + (size_t)r * Wp + wp_p) * 98 + 2 * k;
            part_off[base]     = accy[p];
            part_off[base + 1] = accx[p];
        }
    }
}

// ============ reduce offset partials + compute (s, src) per (pixel, tap) ====
__global__ __launch_bounds__(256) void k_sparams(
    const float* __restrict__ part_off, const float* __restrict__ OB,
    float* __restrict__ SW, int* __restrict__ SIDX,
    const int npix, const int CG,
    const int H, const int W, const int Hp, const int Wp, const int pix0)
{
    const int gid = blockIdx.x * 256 + threadIdx.x;
    if (gid >= npix * K49) return;
    const int pixL = gid / K49;
    const int k = gid - pixL * K49;
    float accy = OB[2 * k], accx = OB[2 * k + 1];
    for (int g = 0; g < CG; ++g) {
        const size_t base = ((size_t)g * npix + pixL) * 98 + 2 * k;
        accy += part_off[base];
        accx += part_off[base + 1];
    }
    const int pixg = pix0 + pixL;
    const int HWp = Hp * Wp;
    const int b = pixg / HWp;
    const int rem = pixg - b * HWp;
    const int hp = rem / Wp;
    const int wp = rem - hp * Wp;

    const float y = (float)(hp + (k / 7) - 3) + accy;
    const float x = (float)(wp + (k % 7) - 3) + accx;
    const float fy0 = floorf(y), fx0 = floorf(x);
    const int iy0 = (int)fy0, ix0 = (int)fx0;
    const float wy1 = y - fy0, wx1 = x - fx0;
    int ye, xe; float wy, wx;
    if (iy0 & 1) { ye = iy0 + 1; wy = wy1; } else { ye = iy0; wy = 1.f - wy1; }
    if (ix0 & 1) { xe = ix0 + 1; wx = wx1; } else { xe = ix0; wx = 1.f - wx1; }
    float s = wy * wx;
    int src = 0;
    if (ye >= 0 && ye < Hp && xe >= 0 && xe < Wp)
        src = (b * H + (ye >> 1)) * W + (xe >> 1);
    else
        s = 0.f;
    SW[gid] = s;
    SIDX[gid] = src;
}

// ============ per-tap GEMM: Y[kg][k][m*F+f] = X[m,:] . W[k][:,f] ============
// Gather-free dense GEMM. Thread tile 4x4, TILE_M = 4096/F.
// grid = (M/TILE_M, 49, KSPLIT); each z-slice covers C/KSPLIT channels.
template<int C, int F, int KSPLIT>
__global__ __launch_bounds__(256) void k_ygemm(
    const float* __restrict__ X,    // [M, C]
    const float* __restrict__ Wt,   // [49, C, F]
    float* __restrict__ Yout,       // [KSPLIT][49][M*F]
    const int M)
{
    constexpr int TILE_M = 4096 / F;
    constexpr int CC = 32;
    constexpr int KC = C / KSPLIT;
    constexpr int NF = F / 4;
    constexpr int LDM = TILE_M + 4;

    __shared__ float Xs[CC][LDM];
    __shared__ float Ws[CC][F];

    const int tid = threadIdx.x;
    const int f0 = (tid % NF) * 4;
    const int m0 = (tid / NF) * 4;
    const int mb = blockIdx.x * TILE_M;
    const int k  = blockIdx.y;
    const int cg = blockIdx.z;
    const int cbase = cg * KC;

    float acc[4][4];
    #pragma unroll
    for (int j = 0; j < 4; ++j)
        #pragma unroll
        for (int i = 0; i < 4; ++i) acc[j][i] = 0.f;

    for (int c0 = 0; c0 < KC; c0 += CC) {
        // stage X tile transposed (c-major)
        for (int e = tid; e < TILE_M * (CC / 4); e += 256) {
            const int m = e / (CC / 4);
            const int c4 = (e % (CC / 4)) * 4;
            const float4 v = *(const float4*)&X[(size_t)(mb + m) * C + cbase + c0 + c4];
            Xs[c4 + 0][m] = v.x;
            Xs[c4 + 1][m] = v.y;
            Xs[c4 + 2][m] = v.z;
            Xs[c4 + 3][m] = v.w;
        }
        // stage W slab
        const float* wg = Wt + ((size_t)k * C + cbase + c0) * F;
        for (int t = tid; t < CC * F / 4; t += 256)
            ((float4*)Ws)[t] = ((const float4*)wg)[t];
        __syncthreads();
        #pragma unroll
        for (int cc = 0; cc < CC; ++cc) {
            const float4 xv = *(const float4*)&Xs[cc][m0];
            const float4 wv = *(const float4*)&Ws[cc][f0];
            acc[0][0] = fmaf(xv.x, wv.x, acc[0][0]);
            acc[0][1] = fmaf(xv.x, wv.y, acc[0][1]);
            acc[0][2] = fmaf(xv.x, wv.z, acc[0][2]);
            acc[0][3] = fmaf(xv.x, wv.w, acc[0][3]);
            acc[1][0] = fmaf(xv.y, wv.x, acc[1][0]);
            acc[1][1] = fmaf(xv.y, wv.y, acc[1][1]);
            acc[1][2] = fmaf(xv.y, wv.z, acc[1][2]);
            acc[1][3] = fmaf(xv.y, wv.w, acc[1][3]);
            acc[2][0] = fmaf(xv.z, wv.x, acc[2][0]);
            acc[2][1] = fmaf(xv.z, wv.y, acc[2][1]);
            acc[2][2] = fmaf(xv.z, wv.z, acc[2][2]);
            acc[2][3] = fmaf(xv.z, wv.w, acc[2][3]);
            acc[3][0] = fmaf(xv.w, wv.x, acc[3][0]);
            acc[3][1] = fmaf(xv.w, wv.y, acc[3][1]);
            acc[3][2] = fmaf(xv.w, wv.z, acc[3][2]);
            acc[3][3] = fmaf(xv.w, wv.w, acc[3][3]);
        }
        __syncthreads();
    }
    float* yb = Yout + ((size_t)(cg * K49 + k)) * M * F;
    #pragma unroll
    for (int j = 0; j < 4; ++j) {
        float4 o = make_float4(acc[j][0], acc[j][1], acc[j][2], acc[j][3]);
        *(float4*)&yb[(size_t)(mb + m0 + j) * F + f0] = o;
    }
}

// ============ sum KSPLIT partial Y slabs ============
__global__ __launch_bounds__(256) void k_reduceY(
    const float* __restrict__ partial, float* __restrict__ Y,
    const int n, const int G)
{
    const int gid = blockIdx.x * 256 + threadIdx.x;
    if (gid >= n) return;
    float a = 0.f;
    for (int g = 0; g < G; ++g) a += partial[(size_t)g * n + gid];
    Y[gid] = a;
}

// ============ combine: out[pix,f] = relu(b_f + sum_k s_k * Y[k][src_k*F+f]) =
template<int F>
__global__ __launch_bounds__(256) void k_combine(
    const float* __restrict__ Y,   // [49][nsrc*F]
    const float* __restrict__ SW, const int* __restrict__ SIDX,
    const float* __restrict__ bias, float* __restrict__ out,
    const int nsrc, const int do_relu)
{
    constexpr int PPB = 256 / F;
    const int tid = threadIdx.x;
    const int f = tid % F;
    const int pix = blockIdx.x * PPB + tid / F;
    const size_t strideY = (size_t)nsrc * F;
    float acc = bias[f];
    #pragma unroll 7
    for (int k = 0; k < K49; ++k) {
        const float s = SW[(size_t)pix * K49 + k];
        const int src = SIDX[(size_t)pix * K49 + k];
        acc = fmaf(s, Y[(size_t)k * strideY + (size_t)src * F + f], acc);
    }
    out[(size_t)pix * F + f] = do_relu ? fmaxf(acc, 0.f) : acc;
}

// ============ stage 4 Y: Y4[k][src] = X3[src,:16] . W4[k,:16] ============
__global__ __launch_bounds__(256) void k_y4(
    const float* __restrict__ X,   // [M,16]
    const float* __restrict__ Wt,  // [49,16]
    float* __restrict__ Y,         // [49][M]
    const int M)
{
    __shared__ float Ws[K49 * 16];
    const int tid = threadIdx.x;
    for (int t = tid; t < K49 * 16; t += 256) Ws[t] = Wt[t];
    __syncthreads();
    const int src = blockIdx.x * 256 + tid;
    const float4* xr = (const float4*)(X + (size_t)src * 16);
    const float4 a0 = xr[0], a1 = xr[1], a2 = xr[2], a3 = xr[3];
    for (int k = 0; k < K49; ++k) {
        const float* wr = Ws + k * 16;
        float d = a0.x*wr[0]  + a0.y*wr[1]  + a0.z*wr[2]  + a0.w*wr[3]
                + a1.x*wr[4]  + a1.y*wr[5]  + a1.z*wr[6]  + a1.w*wr[7]
                + a2.x*wr[8]  + a2.y*wr[9]  + a2.z*wr[10] + a2.w*wr[11]
                + a3.x*wr[12] + a3.y*wr[13] + a3.z*wr[14] + a3.w*wr[15];
        Y[(size_t)k * M + src] = d;
    }
}

// ============ stage 4: fused sparams + gather-combine via Y4, 4-lane split ===
__global__ __launch_bounds__(256) void k_dconv_f1_y(
    const float* __restrict__ Y4,       // [49][nsrc]
    const float* __restrict__ part,     // [npix, 98] raw offset conv (no bias)
    const float* __restrict__ OB,       // [98]
    const float* __restrict__ bias, float* __restrict__ out,
    const int H, const int W, const int Hp, const int Wp,
    const int pix0, const int nsrc)
{
    __shared__ float OBs[98];
    const int tid = threadIdx.x;
    if (tid < 98) OBs[tid] = OB[tid];
    __syncthreads();

    const int pixL = blockIdx.x * 64 + (tid >> 2);
    const int tq = tid & 3;
    const int t0 = (tq == 0) ? 0 : 13 + (tq - 1) * 12;
    const int t1 = t0 + ((tq == 0) ? 13 : 12);

    const int pixg = pix0 + pixL;
    const int HWp = Hp * Wp;
    const int b = pixg / HWp;
    const int rem = pixg - b * HWp;
    const int hp = rem / Wp;
    const int wp = rem - hp * Wp;

    float acc = 0.f;
    for (int k = t0; k < t1; ++k) {
        const float offy = part[(size_t)pixL * 98 + 2 * k]     + OBs[2 * k];
        const float offx = part[(size_t)pixL * 98 + 2 * k + 1] + OBs[2 * k + 1];
        const float y = (float)(hp + (k / 7) - 3) + offy;
        const float x = (float)(wp + (k % 7) - 3) + offx;
        const float fy0 = floorf(y), fx0 = floorf(x);
        const int iy0 = (int)fy0, ix0 = (int)fx0;
        const float wy1 = y - fy0, wx1 = x - fx0;
        int ye, xe; float wy, wx;
        if (iy0 & 1) { ye = iy0 + 1; wy = wy1; } else { ye = iy0; wy = 1.f - wy1; }
        if (ix0 & 1) { xe = ix0 + 1; wx = wx1; } else { xe = ix0; wx = 1.f - wx1; }
        float s = wy * wx;
        int src = 0;
        if (ye >= 0 && ye < Hp && xe >= 0 && xe < Wp)
            src = (b * H + (ye >> 1)) * W + (xe >> 1);
        else
            s = 0.f;
        acc = fmaf(s, Y4[(size_t)k * nsrc + src], acc);
    }
    acc += __shfl_xor(acc, 1);
    acc += __shfl_xor(acc, 2);
    if (tq == 0) out[pixg] = acc + bias[0];
}

extern "C" void kernel_launch(void* const* d_in, const int* in_sizes, int n_in,
                              void* d_out, int out_size, void* d_ws, size_t ws_size,
                              hipStream_t stream) {
    const float* z   = (const float*)d_in[0];
    const float* dw  = (const float*)d_in[1];
    const float* db  = (const float*)d_in[2];
    const float* ow1 = (const float*)d_in[3];
    const float* ob1 = (const float*)d_in[4];
    const float* w1  = (const float*)d_in[5];
    const float* b1  = (const float*)d_in[6];
    const float* ow2 = (const float*)d_in[7];
    const float* ob2 = (const float*)d_in[8];
    const float* w2  = (const float*)d_in[9];
    const float* b2  = (const float*)d_in[10];
    const float* ow3 = (const float*)d_in[11];
    const float* ob3 = (const float*)d_in[12];
    const float* w3  = (const float*)d_in[13];
    const float* b3  = (const float*)d_in[14];
    const float* ow4 = (const float*)d_in[15];
    const float* ob4 = (const float*)d_in[16];
    const float* w4  = (const float*)d_in[17];
    const float* b4  = (const float*)d_in[18];

    // workspace layout (floats): total 6,537,216 floats = 26.1 MB
    float* ws   = (float*)d_ws;
    float* x0   = ws;                      // 262144  [2,8,16,1024]
    float* x1   = x0 + 262144;             // 65536   [2,16,32,64]
    float* x2   = x1 + 65536;              // 131072  [2,32,64,32]
    float* x3   = x2 + 131072;             // 262144  [2,64,128,16]
    float* sw   = x3 + 262144;             // 802816  (16384 pix * 49)
    int*   sidx = (int*)(sw + 802816);     // 802816
    float* part = (float*)(sidx + 802816); // 3407872 (off-partials / Y-partials / Y2 / Y3)
    float* Ybuf = part + 3407872;          // 802816  (Y1: 49*256*64; Y4: 49*16384)

    float* out = (float*)d_out;

    // ---- dense + relu ----
    k_dense_relu<<<512, 256, 0, stream>>>(z, dw, db, x0);

    // ---- stage 1: x0 [2,8,16,1024] -> x1 [2,16,32,64] (nsrc=256, npix=1024) ----
    {
        const int H = 8, W = 16, Hp = 16, Wp = 32, npix = 1024, nsrc = 256, CG = 32;
        dim3 go((npix / Wp) * 2 * (W / 16), CG);
        k_offgemm<1024, 32><<<go, 64, 0, stream>>>(x0, H, W, ow1, part, Hp, Wp, 0, npix);
        k_sparams<<<(npix * K49 + 255) / 256, 256, 0, stream>>>(part, ob1, sw, sidx, npix, CG, H, W, Hp, Wp, 0);
        dim3 gy(nsrc * 64 / 4096, K49, 4);
        k_ygemm<1024, 64, 4><<<gy, 256, 0, stream>>>(x0, w1, part, nsrc);
        const int nY = K49 * nsrc * 64;
        k_reduceY<<<(nY + 255) / 256, 256, 0, stream>>>(part, Ybuf, nY, 4);
        k_combine<64><<<npix * 64 / 256, 256, 0, stream>>>(Ybuf, sw, sidx, b1, x1, nsrc, 1);
    }

    // ---- stage 2: x1 [2,16,32,64] -> x2 [2,32,64,32] (nsrc=1024, npix=4096) ----
    {
        const int H = 16, W = 32, Hp = 32, Wp = 64, npix = 4096, nsrc = 1024, CG = 2;
        dim3 go((npix / Wp) * 2 * (W / 16), CG);
        k_offgemm<64, 32><<<go, 64, 0, stream>>>(x1, H, W, ow2, part, Hp, Wp, 0, npix);
        k_sparams<<<(npix * K49 + 255) / 256, 256, 0, stream>>>(part, ob2, sw, sidx, npix, CG, H, W, Hp, Wp, 0);
        dim3 gy(nsrc * 32 / 4096, K49, 1);
        k_ygemm<64, 32, 1><<<gy, 256, 0, stream>>>(x1, w2, part, nsrc);   // Y2 lives in part
        k_combine<32><<<npix * 32 / 256, 256, 0, stream>>>(part, sw, sidx, b2, x2, nsrc, 1);
    }

    // ---- stage 3: x2 [2,32,64,32] -> x3 [2,64,128,16] (nsrc=4096, npix=16384) ----
    {
        const int H = 32, W = 64, Hp = 64, Wp = 128, npix = 16384, nsrc = 4096, CG = 1;
        dim3 go((npix / Wp) * 2 * (W / 16), CG);
        k_offgemm<32, 32><<<go, 64, 0, stream>>>(x2, H, W, ow3, part, Hp, Wp, 0, npix);
        k_sparams<<<(npix * K49 + 255) / 256, 256, 0, stream>>>(part, ob3, sw, sidx, npix, CG, H, W, Hp, Wp, 0);
        dim3 gy(nsrc * 16 / 4096, K49, 1);
        k_ygemm<32, 16, 1><<<gy, 256, 0, stream>>>(x2, w3, part, nsrc);   // Y3 lives in part
        k_combine<16><<<npix * 16 / 256, 256, 0, stream>>>(part, sw, sidx, b3, x3, nsrc, 1);
    }

    // ---- stage 4: x3 [2,64,128,16] -> out [2,128,256,1] (nsrc=16384) ----
    {
        const int H = 64, W = 128, Hp = 128, Wp = 256, CHUNK = 16384, nsrc = 16384;
        k_y4<<<nsrc / 256, 256, 0, stream>>>(x3, w4, Ybuf, nsrc);
        for (int c = 0; c < 4; ++c) {
            const int pix0 = c * CHUNK;
            dim3 go((CHUNK / Wp) * 2 * (W / 16), 1);
            k_offgemm<16, 16><<<go, 64, 0, stream>>>(x3, H, W, ow4, part, Hp, Wp, pix0, CHUNK);
            k_dconv_f1_y<<<CHUNK / 64, 256, 0, stream>>>(Ybuf, part, ob4, b4, out, H, W, Hp, Wp, pix0, nsrc);
        }
    }
}

// Round 4
// 381.694 us; speedup vs baseline: 2.0428x; 1.2687x over previous
//
#include <hip/hip_runtime.h>

#define K49 49

// ============ dense (z @ W + b) + relu -> x0 [2,8,16,1024] ============
__global__ __launch_bounds__(256) void k_dense_relu(
    const float* __restrict__ z, const float* __restrict__ Wd,
    const float* __restrict__ bd, float* __restrict__ x0)
{
    const int D = 131072;
    __shared__ float zs[256];
    const int tid = threadIdx.x;
    zs[tid] = z[tid];                 // z is [2,128] = 256 floats
    __syncthreads();
    const int n = blockIdx.x * 256 + tid;
    const float bb = bd[n];
    float a0 = bb, a1 = bb;
    #pragma unroll 8
    for (int kk = 0; kk < 128; ++kk) {
        const float w = Wd[kk * D + n];
        a0 = fmaf(zs[kk], w, a0);
        a1 = fmaf(zs[128 + kk], w, a1);
    }
    x0[n]     = fmaxf(a0, 0.f);
    x0[D + n] = fmaxf(a1, 0.f);
}

// ============ offset conv, v2: 4 waves/block share one parity class =========
// Jobs (row, wtile) of the same parity class (hp&1, rx) have an identical
// valid-tap set; 4 such jobs per block. OW tap-slice is register-prefetched
// and LDS-staged (coalesced float2), so all FMA operands come from LDS.
// part_off layout: [CG][npix][98]
template<int C, int CC>
__global__ __launch_bounds__(256) void k_offgemm2(
    const float* __restrict__ X, const int H, const int W,
    const float* __restrict__ OW,      // [7,7,C,98]
    float* __restrict__ part_off,
    const int Hp, const int Wp, const int pix0, const int npix)
{
    constexpr int P = 16;
    constexpr int NPF = (CC * 49 + 255) / 256;   // float2 prefetches/thread

    const int tid = threadIdx.x;
    const int wv  = tid >> 6;
    const int k   = tid & 63;
    const int kc  = (k < 48) ? k : 48;
    const int cg  = blockIdx.y;

    const int W2  = W / P;
    const int R   = npix / Wp;          // padded rows in this chunk
    const int jpc = (R / 2) * W2;       // jobs per parity class
    const int bpc = jpc / 4;            // blocks per class
    const int cls = blockIdx.x / bpc;
    const int jb0 = (blockIdx.x - cls * bpc) * 4;
    const int pi  = cls >> 1;           // hp parity
    const int rho = cls & 1;            // x parity

    const int jc = jb0 + wv;
    const int rr = jc / W2;
    const int wt = jc - rr * W2;
    const int r  = 2 * rr + pi;         // pix0/Wp is even at every call site
    const int w0 = wt * P;
    const int grow = pix0 / Wp + r;
    const int b   = grow / Hp;
    const int hp  = grow - b * Hp;
    const int ys_lo = (hp - 2) >> 1;

    const int NR = pi ? 4 : 3;
    const int di0 = pi ? 0 : 1;
    const int NC = rho ? 4 : 3;
    const int dj0 = rho ? 0 : 1;
    const int T = NR * NC;

    __shared__ float OWs[CC * 98];
    __shared__ float Xs[4][4][19][CC];

    const int cbase = cg * CC;

    // per-wave Xs stage (float4 along c)
    for (int e = k; e < 4 * 19 * (CC / 4); e += 64) {
        const int tr = e / (19 * (CC / 4));
        const int rm = e - tr * (19 * (CC / 4));
        const int tc = rm / (CC / 4);
        const int c4 = (rm - tc * (CC / 4)) * 4;
        const int ys = ys_lo + tr;
        const int xs = w0 - 1 + tc;
        float4 v = make_float4(0.f, 0.f, 0.f, 0.f);
        if (ys >= 0 && ys < H && xs >= 0 && xs < W)
            v = *(const float4*)&X[((size_t)((b * H + ys) * W + xs)) * C + cbase + c4];
        Xs[wv][tr][tc][c4 + 0] = v.x;
        Xs[wv][tr][tc][c4 + 1] = v.y;
        Xs[wv][tr][tc][c4 + 2] = v.z;
        Xs[wv][tr][tc][c4 + 3] = v.w;
    }

    float accy[P], accx[P];
    #pragma unroll
    for (int p = 0; p < P; ++p) { accy[p] = 0.f; accx[p] = 0.f; }

    float2* owf2 = (float2*)OWs;
    const int NE = CC * 49;

    // prefetch tap 0
    float2 pf[NPF];
    {
        const float2* src = (const float2*)(OW + ((size_t)((di0 * 7 + dj0) * C + cbase)) * 98);
        #pragma unroll
        for (int i = 0; i < NPF; ++i) {
            int e = tid + i * 256; if (e > NE - 1) e = NE - 1;
            pf[i] = src[e];
        }
    }

    int tr = 0, tcp = 0;
    for (int t = 0; t < T; ++t) {
        __syncthreads();                       // prior readers of OWs done
        #pragma unroll
        for (int i = 0; i < NPF; ++i) {
            const int e = tid + i * 256;
            if (e < NE) owf2[e] = pf[i];
        }
        __syncthreads();                       // OWs ready
        if (t + 1 < T) {                       // issue prefetch of next tap
            int tcn = tcp + 1, trn = tr;
            if (tcn == NC) { tcn = 0; trn = tr + 1; }
            const int di = di0 + 2 * trn, dj = dj0 + 2 * tcn;
            const float2* src = (const float2*)(OW + ((size_t)((di * 7 + dj) * C + cbase)) * 98);
            #pragma unroll
            for (int i = 0; i < NPF; ++i) {
                int e = tid + i * 256; if (e > NE - 1) e = NE - 1;
                pf[i] = src[e];
            }
        }
        // compute tap t from LDS
        #pragma unroll
        for (int cc4 = 0; cc4 < CC; cc4 += 4) {
            const float2 o0 = owf2[(cc4 + 0) * 49 + kc];
            const float2 o1 = owf2[(cc4 + 1) * 49 + kc];
            const float2 o2 = owf2[(cc4 + 2) * 49 + kc];
            const float2 o3 = owf2[(cc4 + 3) * 49 + kc];
            #pragma unroll
            for (int p = 0; p < P; ++p) {
                const float4 xv = *(const float4*)&Xs[wv][tr][p + tcp][cc4];
                accy[p] = fmaf(xv.x, o0.x, accy[p]);
                accx[p] = fmaf(xv.x, o0.y, accx[p]);
                accy[p] = fmaf(xv.y, o1.x, accy[p]);
                accx[p] = fmaf(xv.y, o1.y, accx[p]);
                accy[p] = fmaf(xv.z, o2.x, accy[p]);
                accx[p] = fmaf(xv.z, o2.y, accx[p]);
                accy[p] = fmaf(xv.w, o3.x, accy[p]);
                accx[p] = fmaf(xv.w, o3.y, accx[p]);
            }
        }
        if (++tcp == NC) { tcp = 0; ++tr; }
    }

    if (k < 49) {
        #pragma unroll
        for (int p = 0; p < P; ++p) {
            const int wp_p = 2 * (w0 + p) + rho;
            const size_t base = ((size_t)cg * npix + (size_t)r * Wp + wp_p) * 98 + 2 * k;
            *(float2*)&part_off[base] = make_float2(accy[p], accx[p]);
        }
    }
}

// ============ reduce offset partials + compute (s, src) per (pixel, tap) ====
__global__ __launch_bounds__(256) void k_sparams(
    const float* __restrict__ part_off, const float* __restrict__ OB,
    float* __restrict__ SW, int* __restrict__ SIDX,
    const int npix, const int CG,
    const int H, const int W, const int Hp, const int Wp, const int pix0)
{
    const int gid = blockIdx.x * 256 + threadIdx.x;
    if (gid >= npix * K49) return;
    const int pixL = gid / K49;
    const int k = gid - pixL * K49;
    float accy = OB[2 * k], accx = OB[2 * k + 1];
    for (int g = 0; g < CG; ++g) {
        const size_t base = ((size_t)g * npix + pixL) * 98 + 2 * k;
        accy += part_off[base];
        accx += part_off[base + 1];
    }
    const int pixg = pix0 + pixL;
    const int HWp = Hp * Wp;
    const int b = pixg / HWp;
    const int rem = pixg - b * HWp;
    const int hp = rem / Wp;
    const int wp = rem - hp * Wp;

    const float y = (float)(hp + (k / 7) - 3) + accy;
    const float x = (float)(wp + (k % 7) - 3) + accx;
    const float fy0 = floorf(y), fx0 = floorf(x);
    const int iy0 = (int)fy0, ix0 = (int)fx0;
    const float wy1 = y - fy0, wx1 = x - fx0;
    int ye, xe; float wy, wx;
    if (iy0 & 1) { ye = iy0 + 1; wy = wy1; } else { ye = iy0; wy = 1.f - wy1; }
    if (ix0 & 1) { xe = ix0 + 1; wx = wx1; } else { xe = ix0; wx = 1.f - wx1; }
    float s = wy * wx;
    int src = 0;
    if (ye >= 0 && ye < Hp && xe >= 0 && xe < Wp)
        src = (b * H + (ye >> 1)) * W + (xe >> 1);
    else
        s = 0.f;
    SW[gid] = s;
    SIDX[gid] = src;
}

// ============ per-tap GEMM: Y[kg][k][m*F+f] = X[m,:] . W[k][:,f] ============
template<int C, int F, int KSPLIT>
__global__ __launch_bounds__(256) void k_ygemm(
    const float* __restrict__ X,    // [M, C]
    const float* __restrict__ Wt,   // [49, C, F]
    float* __restrict__ Yout,       // [KSPLIT][49][M*F]
    const int M)
{
    constexpr int TILE_M = 4096 / F;
    constexpr int CC = 32;
    constexpr int KC = C / KSPLIT;
    constexpr int NF = F / 4;
    constexpr int LDM = TILE_M + 4;

    __shared__ float Xs[CC][LDM];
    __shared__ float Ws[CC][F];

    const int tid = threadIdx.x;
    const int f0 = (tid % NF) * 4;
    const int m0 = (tid / NF) * 4;
    const int mb = blockIdx.x * TILE_M;
    const int k  = blockIdx.y;
    const int cg = blockIdx.z;
    const int cbase = cg * KC;

    float acc[4][4];
    #pragma unroll
    for (int j = 0; j < 4; ++j)
        #pragma unroll
        for (int i = 0; i < 4; ++i) acc[j][i] = 0.f;

    for (int c0 = 0; c0 < KC; c0 += CC) {
        for (int e = tid; e < TILE_M * (CC / 4); e += 256) {
            const int m = e / (CC / 4);
            const int c4 = (e % (CC / 4)) * 4;
            const float4 v = *(const float4*)&X[(size_t)(mb + m) * C + cbase + c0 + c4];
            Xs[c4 + 0][m] = v.x;
            Xs[c4 + 1][m] = v.y;
            Xs[c4 + 2][m] = v.z;
            Xs[c4 + 3][m] = v.w;
        }
        const float* wg = Wt + ((size_t)k * C + cbase + c0) * F;
        for (int t = tid; t < CC * F / 4; t += 256)
            ((float4*)Ws)[t] = ((const float4*)wg)[t];
        __syncthreads();
        #pragma unroll
        for (int cc = 0; cc < CC; ++cc) {
            const float4 xv = *(const float4*)&Xs[cc][m0];
            const float4 wv = *(const float4*)&Ws[cc][f0];
            acc[0][0] = fmaf(xv.x, wv.x, acc[0][0]);
            acc[0][1] = fmaf(xv.x, wv.y, acc[0][1]);
            acc[0][2] = fmaf(xv.x, wv.z, acc[0][2]);
            acc[0][3] = fmaf(xv.x, wv.w, acc[0][3]);
            acc[1][0] = fmaf(xv.y, wv.x, acc[1][0]);
            acc[1][1] = fmaf(xv.y, wv.y, acc[1][1]);
            acc[1][2] = fmaf(xv.y, wv.z, acc[1][2]);
            acc[1][3] = fmaf(xv.y, wv.w, acc[1][3]);
            acc[2][0] = fmaf(xv.z, wv.x, acc[2][0]);
            acc[2][1] = fmaf(xv.z, wv.y, acc[2][1]);
            acc[2][2] = fmaf(xv.z, wv.z, acc[2][2]);
            acc[2][3] = fmaf(xv.z, wv.w, acc[2][3]);
            acc[3][0] = fmaf(xv.w, wv.x, acc[3][0]);
            acc[3][1] = fmaf(xv.w, wv.y, acc[3][1]);
            acc[3][2] = fmaf(xv.w, wv.z, acc[3][2]);
            acc[3][3] = fmaf(xv.w, wv.w, acc[3][3]);
        }
        __syncthreads();
    }
    float* yb = Yout + ((size_t)(cg * K49 + k)) * M * F;
    #pragma unroll
    for (int j = 0; j < 4; ++j) {
        float4 o = make_float4(acc[j][0], acc[j][1], acc[j][2], acc[j][3]);
        *(float4*)&yb[(size_t)(mb + m0 + j) * F + f0] = o;
    }
}

// ============ sum KSPLIT partial Y slabs ============
__global__ __launch_bounds__(256) void k_reduceY(
    const float* __restrict__ partial, float* __restrict__ Y,
    const int n, const int G)
{
    const int gid = blockIdx.x * 256 + threadIdx.x;
    if (gid >= n) return;
    float a = 0.f;
    for (int g = 0; g < G; ++g) a += partial[(size_t)g * n + gid];
    Y[gid] = a;
}

// ============ combine: out[pix,f] = relu(b_f + sum_k s_k * Y[k][src_k*F+f]) =
template<int F>
__global__ __launch_bounds__(256) void k_combine(
    const float* __restrict__ Y,   // [49][nsrc*F]
    const float* __restrict__ SW, const int* __restrict__ SIDX,
    const float* __restrict__ bias, float* __restrict__ out,
    const int nsrc, const int do_relu)
{
    constexpr int PPB = 256 / F;
    const int tid = threadIdx.x;
    const int f = tid % F;
    const int pix = blockIdx.x * PPB + tid / F;
    const size_t strideY = (size_t)nsrc * F;
    float acc = bias[f];
    #pragma unroll 7
    for (int k = 0; k < K49; ++k) {
        const float s = SW[(size_t)pix * K49 + k];
        const int src = SIDX[(size_t)pix * K49 + k];
        acc = fmaf(s, Y[(size_t)k * strideY + (size_t)src * F + f], acc);
    }
    out[(size_t)pix * F + f] = do_relu ? fmaxf(acc, 0.f) : acc;
}

// ============ stage 4 Y: Y4[k][src] = X3[src,:16] . W4[k,:16] ============
__global__ __launch_bounds__(256) void k_y4(
    const float* __restrict__ X,   // [M,16]
    const float* __restrict__ Wt,  // [49,16]
    float* __restrict__ Y,         // [49][M]
    const int M)
{
    __shared__ float Ws[K49 * 16];
    const int tid = threadIdx.x;
    for (int t = tid; t < K49 * 16; t += 256) Ws[t] = Wt[t];
    __syncthreads();
    const int src = blockIdx.x * 256 + tid;
    const float4* xr = (const float4*)(X + (size_t)src * 16);
    const float4 a0 = xr[0], a1 = xr[1], a2 = xr[2], a3 = xr[3];
    for (int k = 0; k < K49; ++k) {
        const float* wr = Ws + k * 16;
        float d = a0.x*wr[0]  + a0.y*wr[1]  + a0.z*wr[2]  + a0.w*wr[3]
                + a1.x*wr[4]  + a1.y*wr[5]  + a1.z*wr[6]  + a1.w*wr[7]
                + a2.x*wr[8]  + a2.y*wr[9]  + a2.z*wr[10] + a2.w*wr[11]
                + a3.x*wr[12] + a3.y*wr[13] + a3.z*wr[14] + a3.w*wr[15];
        Y[(size_t)k * M + src] = d;
    }
}

// ============ stage 4: fused sparams + gather-combine via Y4, 4-lane split ===
__global__ __launch_bounds__(256) void k_dconv_f1_y(
    const float* __restrict__ Y4,       // [49][nsrc]
    const float* __restrict__ part,     // [npix, 98] raw offset conv (no bias)
    const float* __restrict__ OB,       // [98]
    const float* __restrict__ bias, float* __restrict__ out,
    const int H, const int W, const int Hp, const int Wp,
    const int pix0, const int nsrc)
{
    __shared__ float OBs[98];
    const int tid = threadIdx.x;
    if (tid < 98) OBs[tid] = OB[tid];
    __syncthreads();

    const int pixL = blockIdx.x * 64 + (tid >> 2);
    const int tq = tid & 3;
    const int t0 = (tq == 0) ? 0 : 13 + (tq - 1) * 12;
    const int t1 = t0 + ((tq == 0) ? 13 : 12);

    const int pixg = pix0 + pixL;
    const int HWp = Hp * Wp;
    const int b = pixg / HWp;
    const int rem = pixg - b * HWp;
    const int hp = rem / Wp;
    const int wp = rem - hp * Wp;

    float acc = 0.f;
    for (int k = t0; k < t1; ++k) {
        const float offy = part[(size_t)pixL * 98 + 2 * k]     + OBs[2 * k];
        const float offx = part[(size_t)pixL * 98 + 2 * k + 1] + OBs[2 * k + 1];
        const float y = (float)(hp + (k / 7) - 3) + offy;
        const float x = (float)(wp + (k % 7) - 3) + offx;
        const float fy0 = floorf(y), fx0 = floorf(x);
        const int iy0 = (int)fy0, ix0 = (int)fx0;
        const float wy1 = y - fy0, wx1 = x - fx0;
        int ye, xe; float wy, wx;
        if (iy0 & 1) { ye = iy0 + 1; wy = wy1; } else { ye = iy0; wy = 1.f - wy1; }
        if (ix0 & 1) { xe = ix0 + 1; wx = wx1; } else { xe = ix0; wx = 1.f - wx1; }
        float s = wy * wx;
        int src = 0;
        if (ye >= 0 && ye < Hp && xe >= 0 && xe < Wp)
            src = (b * H + (ye >> 1)) * W + (xe >> 1);
        else
            s = 0.f;
        acc = fmaf(s, Y4[(size_t)k * nsrc + src], acc);
    }
    acc += __shfl_xor(acc, 1);
    acc += __shfl_xor(acc, 2);
    if (tq == 0) out[pixg] = acc + bias[0];
}

extern "C" void kernel_launch(void* const* d_in, const int* in_sizes, int n_in,
                              void* d_out, int out_size, void* d_ws, size_t ws_size,
                              hipStream_t stream) {
    const float* z   = (const float*)d_in[0];
    const float* dw  = (const float*)d_in[1];
    const float* db  = (const float*)d_in[2];
    const float* ow1 = (const float*)d_in[3];
    const float* ob1 = (const float*)d_in[4];
    const float* w1  = (const float*)d_in[5];
    const float* b1  = (const float*)d_in[6];
    const float* ow2 = (const float*)d_in[7];
    const float* ob2 = (const float*)d_in[8];
    const float* w2  = (const float*)d_in[9];
    const float* b2  = (const float*)d_in[10];
    const float* ow3 = (const float*)d_in[11];
    const float* ob3 = (const float*)d_in[12];
    const float* w3  = (const float*)d_in[13];
    const float* b3  = (const float*)d_in[14];
    const float* ow4 = (const float*)d_in[15];
    const float* ob4 = (const float*)d_in[16];
    const float* w4  = (const float*)d_in[17];
    const float* b4  = (const float*)d_in[18];

    // workspace layout (floats): total 6,537,216 floats = 26.1 MB
    float* ws   = (float*)d_ws;
    float* x0   = ws;                      // 262144  [2,8,16,1024]
    float* x1   = x0 + 262144;             // 65536   [2,16,32,64]
    float* x2   = x1 + 65536;              // 131072  [2,32,64,32]
    float* x3   = x2 + 131072;             // 262144  [2,64,128,16]
    float* sw   = x3 + 262144;             // 802816  (16384 pix * 49)
    int*   sidx = (int*)(sw + 802816);     // 802816
    float* part = (float*)(sidx + 802816); // 3407872 (off-partials / Y-partials / Y2 / Y3)
    float* Ybuf = part + 3407872;          // 802816  (Y1: 49*256*64; Y4: 49*16384)

    float* out = (float*)d_out;

    // ---- dense + relu ----
    k_dense_relu<<<512, 256, 0, stream>>>(z, dw, db, x0);

    // ---- stage 1: x0 [2,8,16,1024] -> x1 [2,16,32,64] (nsrc=256, npix=1024) ----
    {
        const int H = 8, W = 16, Hp = 16, Wp = 32, npix = 1024, nsrc = 256, CG = 32;
        // jobs/class = (npix/Wp/2)*(W/16) = 16 -> 4 blocks/class -> grid.x = 16
        dim3 go(16, CG);
        k_offgemm2<1024, 32><<<go, 256, 0, stream>>>(x0, H, W, ow1, part, Hp, Wp, 0, npix);
        k_sparams<<<(npix * K49 + 255) / 256, 256, 0, stream>>>(part, ob1, sw, sidx, npix, CG, H, W, Hp, Wp, 0);
        dim3 gy(nsrc * 64 / 4096, K49, 4);
        k_ygemm<1024, 64, 4><<<gy, 256, 0, stream>>>(x0, w1, part, nsrc);
        const int nY = K49 * nsrc * 64;
        k_reduceY<<<(nY + 255) / 256, 256, 0, stream>>>(part, Ybuf, nY, 4);
        k_combine<64><<<npix * 64 / 256, 256, 0, stream>>>(Ybuf, sw, sidx, b1, x1, nsrc, 1);
    }

    // ---- stage 2: x1 [2,16,32,64] -> x2 [2,32,64,32] (nsrc=1024, npix=4096) ----
    {
        const int H = 16, W = 32, Hp = 32, Wp = 64, npix = 4096, nsrc = 1024, CG = 2;
        // jobs/class = 32*2 = 64 -> grid.x = 64
        dim3 go(64, CG);
        k_offgemm2<64, 32><<<go, 256, 0, stream>>>(x1, H, W, ow2, part, Hp, Wp, 0, npix);
        k_sparams<<<(npix * K49 + 255) / 256, 256, 0, stream>>>(part, ob2, sw, sidx, npix, CG, H, W, Hp, Wp, 0);
        dim3 gy(nsrc * 32 / 4096, K49, 1);
        k_ygemm<64, 32, 1><<<gy, 256, 0, stream>>>(x1, w2, part, nsrc);   // Y2 lives in part
        k_combine<32><<<npix * 32 / 256, 256, 0, stream>>>(part, sw, sidx, b2, x2, nsrc, 1);
    }

    // ---- stage 3: x2 [2,32,64,32] -> x3 [2,64,128,16] (nsrc=4096, npix=16384) ----
    {
        const int H = 32, W = 64, Hp = 64, Wp = 128, npix = 16384, nsrc = 4096, CG = 1;
        // jobs/class = 64*4 = 256 -> grid.x = 256
        dim3 go(256, CG);
        k_offgemm2<32, 32><<<go, 256, 0, stream>>>(x2, H, W, ow3, part, Hp, Wp, 0, npix);
        k_sparams<<<(npix * K49 + 255) / 256, 256, 0, stream>>>(part, ob3, sw, sidx, npix, CG, H, W, Hp, Wp, 0);
        dim3 gy(nsrc * 16 / 4096, K49, 1);
        k_ygemm<32, 16, 1><<<gy, 256, 0, stream>>>(x2, w3, part, nsrc);   // Y3 lives in part
        k_combine<16><<<npix * 16 / 256, 256, 0, stream>>>(part, sw, sidx, b3, x3, nsrc, 1);
    }

    // ---- stage 4: x3 [2,64,128,16] -> out [2,128,256,1] (nsrc=16384), 2 chunks ----
    {
        const int H = 64, W = 128, Hp = 128, Wp = 256, CHUNK = 32768, nsrc = 16384;
        k_y4<<<nsrc / 256, 256, 0, stream>>>(x3, w4, Ybuf, nsrc);
        for (int c = 0; c < 2; ++c) {
            const int pix0 = c * CHUNK;
            // jobs/class = (128/2)*8 = 512 -> grid.x = 512
            dim3 go(512, 1);
            k_offgemm2<16, 16><<<go, 256, 0, stream>>>(x3, H, W, ow4, part, Hp, Wp, pix0, CHUNK);
            k_dconv_f1_y<<<CHUNK / 64, 256, 0, stream>>>(Ybuf, part, ob4, b4, out, H, W, Hp, Wp, pix0, nsrc);
        }
    }
}

// Round 5
// 326.840 us; speedup vs baseline: 2.3857x; 1.1678x over previous
//
#include <hip/hip_runtime.h>

#define K49 49

// ============ dense (z @ W + b) + relu -> x0 [2,8,16,1024] ============
__global__ __launch_bounds__(256) void k_dense_relu(
    const float* __restrict__ z, const float* __restrict__ Wd,
    const float* __restrict__ bd, float* __restrict__ x0)
{
    const int D = 131072;
    __shared__ float zs[256];
    const int tid = threadIdx.x;
    zs[tid] = z[tid];                 // z is [2,128] = 256 floats
    __syncthreads();
    const int n = blockIdx.x * 256 + tid;
    const float bb = bd[n];
    float a0 = bb, a1 = bb;
    #pragma unroll 8
    for (int kk = 0; kk < 128; ++kk) {
        const float w = Wd[kk * D + n];
        a0 = fmaf(zs[kk], w, a0);
        a1 = fmaf(zs[128 + kk], w, a1);
    }
    x0[n]     = fmaxf(a0, 0.f);
    x0[D + n] = fmaxf(a1, 0.f);
}

// ============ offset conv, v3: one job per block, 4 waves split channels ====
// A "job" = (padded row r, x-parity rho, 16-px tile). All taps with source
// coord (even,even) contribute; tap set is uniform per parity class.
// Wave wv covers channels [wv*CC/4, (wv+1)*CC/4) of this block's CC-chunk;
// cross-wave reduction via LDS at the end. OW tap-slice is register-
// prefetched then LDS-staged; Xs is one shared slab for all 4 waves.
// part_off layout: [CG][npix][98]
template<int C, int CC>
__global__ __launch_bounds__(256) void k_offgemm3(
    const float* __restrict__ X, const int H, const int W,
    const float* __restrict__ OW,      // [7,7,C,98]
    float* __restrict__ part_off,
    const int Hp, const int Wp, const int pix0, const int npix)
{
    constexpr int P = 16;
    constexpr int CW = CC / 4;                    // channels per wave
    constexpr int NPF = (CC * 49 + 255) / 256;    // float2 prefetches/thread
    constexpr int LDSZ = (174 * CC > 6272) ? 174 * CC : 6272;

    const int tid = threadIdx.x;
    const int wv  = tid >> 6;
    const int k   = tid & 63;
    const int kc  = (k < 48) ? k : 48;
    const int cg  = blockIdx.y;

    const int W2  = W / P;
    const int R   = npix / Wp;          // padded rows in this chunk
    const int jpc = (R / 2) * W2;       // jobs per parity class
    const int cls = blockIdx.x / jpc;
    const int jc  = blockIdx.x - cls * jpc;
    const int pi  = cls >> 1;           // hp parity
    const int rho = cls & 1;            // x parity
    const int rr  = jc / W2;
    const int wt  = jc - rr * W2;
    const int r   = 2 * rr + pi;        // pix0/Wp is even at every call site
    const int w0  = wt * P;
    const int grow = pix0 / Wp + r;
    const int b   = grow / Hp;
    const int hp  = grow - b * Hp;
    const int ys_lo = (hp - 2) >> 1;

    const int NR = pi ? 4 : 3;
    const int di0 = pi ? 0 : 1;
    const int NC = rho ? 4 : 3;
    const int dj0 = rho ? 0 : 1;
    const int T = NR * NC;

    __shared__ float lds[LDSZ];
    float*  OWs  = lds;                 // CC*98 floats
    float*  Xs   = lds + CC * 98;       // [4][19][CC]
    float2* owf2 = (float2*)OWs;
    float2* red2 = (float2*)lds;        // [4][16*49] (reused after compute)

    const int cbase = cg * CC;

    // stage Xs cooperatively (float4 along c)
    {
        constexpr int CCq = CC / 4;
        for (int e = tid; e < 76 * CCq; e += 256) {
            const int tr = e / (19 * CCq);
            const int rm = e - tr * 19 * CCq;
            const int tc = rm / CCq;
            const int c4 = (rm - tc * CCq) * 4;
            const int ys = ys_lo + tr;
            const int xs = w0 - 1 + tc;
            float4 v = make_float4(0.f, 0.f, 0.f, 0.f);
            if (ys >= 0 && ys < H && xs >= 0 && xs < W)
                v = *(const float4*)&X[((size_t)((b * H + ys) * W + xs)) * C + cbase + c4];
            *(float4*)&Xs[(tr * 19 + tc) * CC + c4] = v;
        }
    }

    float accy[P], accx[P];
    #pragma unroll
    for (int p = 0; p < P; ++p) { accy[p] = 0.f; accx[p] = 0.f; }

    const int NE = CC * 49;

    // prefetch tap 0
    float2 pf[NPF];
    {
        const float2* src = (const float2*)(OW + ((size_t)((di0 * 7 + dj0) * C + cbase)) * 98);
        #pragma unroll
        for (int i = 0; i < NPF; ++i) {
            int e = tid + i * 256; if (e > NE - 1) e = NE - 1;
            pf[i] = src[e];
        }
    }

    const int cw0 = wv * CW;
    int tr = 0, tcp = 0;
    for (int t = 0; t < T; ++t) {
        __syncthreads();                       // prior readers of OWs done (and Xs staged)
        #pragma unroll
        for (int i = 0; i < NPF; ++i) {
            const int e = tid + i * 256;
            if (e < NE) owf2[e] = pf[i];
        }
        __syncthreads();                       // OWs ready
        if (t + 1 < T) {                       // issue prefetch of next tap
            int tcn = tcp + 1, trn = tr;
            if (tcn == NC) { tcn = 0; trn = tr + 1; }
            const int di = di0 + 2 * trn, dj = dj0 + 2 * tcn;
            const float2* src = (const float2*)(OW + ((size_t)((di * 7 + dj) * C + cbase)) * 98);
            #pragma unroll
            for (int i = 0; i < NPF; ++i) {
                int e = tid + i * 256; if (e > NE - 1) e = NE - 1;
                pf[i] = src[e];
            }
        }
        // compute tap t from LDS, this wave's channel slice
        #pragma unroll
        for (int s = 0; s < CW / 4; ++s) {
            const int cc4 = cw0 + s * 4;
            const float2 o0 = owf2[(cc4 + 0) * 49 + kc];
            const float2 o1 = owf2[(cc4 + 1) * 49 + kc];
            const float2 o2 = owf2[(cc4 + 2) * 49 + kc];
            const float2 o3 = owf2[(cc4 + 3) * 49 + kc];
            #pragma unroll
            for (int p = 0; p < P; ++p) {
                const float4 xv = *(const float4*)&Xs[(tr * 19 + p + tcp) * CC + cc4];
                accy[p] = fmaf(xv.x, o0.x, accy[p]);
                accx[p] = fmaf(xv.x, o0.y, accx[p]);
                accy[p] = fmaf(xv.y, o1.x, accy[p]);
                accx[p] = fmaf(xv.y, o1.y, accx[p]);
                accy[p] = fmaf(xv.z, o2.x, accy[p]);
                accx[p] = fmaf(xv.z, o2.y, accx[p]);
                accy[p] = fmaf(xv.w, o3.x, accy[p]);
                accx[p] = fmaf(xv.w, o3.y, accx[p]);
            }
        }
        if (++tcp == NC) { tcp = 0; ++tr; }
    }

    // cross-wave reduce via LDS (reuses OWs/Xs space), coalesced final write
    __syncthreads();
    if (k < 49) {
        #pragma unroll
        for (int p = 0; p < P; ++p)
            red2[(wv * 16 + p) * 49 + k] = make_float2(accy[p], accx[p]);
    }
    __syncthreads();
    const size_t rowbase = (size_t)cg * npix + (size_t)r * Wp;
    for (int e = tid; e < 784; e += 256) {
        const int p  = e / 49;
        const int kk = e - p * 49;
        const float2 v0 = red2[e];
        const float2 v1 = red2[784 + e];
        const float2 v2 = red2[1568 + e];
        const float2 v3 = red2[2352 + e];
        const float2 v = make_float2(v0.x + v1.x + v2.x + v3.x,
                                     v0.y + v1.y + v2.y + v3.y);
        const int wp_p = 2 * (w0 + p) + rho;
        *(float2*)&part_off[(rowbase + wp_p) * 98 + 2 * kk] = v;
    }
}

// ============ reduce offset partials + compute (s, src) per (pixel, tap) ====
__global__ __launch_bounds__(256) void k_sparams(
    const float* __restrict__ part_off, const float* __restrict__ OB,
    float* __restrict__ SW, int* __restrict__ SIDX,
    const int npix, const int CG,
    const int H, const int W, const int Hp, const int Wp, const int pix0)
{
    const int gid = blockIdx.x * 256 + threadIdx.x;
    if (gid >= npix * K49) return;
    const int pixL = gid / K49;
    const int k = gid - pixL * K49;
    float accy = OB[2 * k], accx = OB[2 * k + 1];
    for (int g = 0; g < CG; ++g) {
        const size_t base = ((size_t)g * npix + pixL) * 98 + 2 * k;
        accy += part_off[base];
        accx += part_off[base + 1];
    }
    const int pixg = pix0 + pixL;
    const int HWp = Hp * Wp;
    const int b = pixg / HWp;
    const int rem = pixg - b * HWp;
    const int hp = rem / Wp;
    const int wp = rem - hp * Wp;

    const float y = (float)(hp + (k / 7) - 3) + accy;
    const float x = (float)(wp + (k % 7) - 3) + accx;
    const float fy0 = floorf(y), fx0 = floorf(x);
    const int iy0 = (int)fy0, ix0 = (int)fx0;
    const float wy1 = y - fy0, wx1 = x - fx0;
    int ye, xe; float wy, wx;
    if (iy0 & 1) { ye = iy0 + 1; wy = wy1; } else { ye = iy0; wy = 1.f - wy1; }
    if (ix0 & 1) { xe = ix0 + 1; wx = wx1; } else { xe = ix0; wx = 1.f - wx1; }
    float s = wy * wx;
    int src = 0;
    if (ye >= 0 && ye < Hp && xe >= 0 && xe < Wp)
        src = (b * H + (ye >> 1)) * W + (xe >> 1);
    else
        s = 0.f;
    SW[gid] = s;
    SIDX[gid] = src;
}

// ============ per-tap GEMM: Y[kg][k][m*F+f] = X[m,:] . W[k][:,f] ============
template<int C, int F, int KSPLIT>
__global__ __launch_bounds__(256) void k_ygemm(
    const float* __restrict__ X,    // [M, C]
    const float* __restrict__ Wt,   // [49, C, F]
    float* __restrict__ Yout,       // [KSPLIT][49][M*F]
    const int M)
{
    constexpr int TILE_M = 4096 / F;
    constexpr int CC = 32;
    constexpr int KC = C / KSPLIT;
    constexpr int NF = F / 4;
    constexpr int LDM = TILE_M + 4;

    __shared__ float Xs[CC][LDM];
    __shared__ float Ws[CC][F];

    const int tid = threadIdx.x;
    const int f0 = (tid % NF) * 4;
    const int m0 = (tid / NF) * 4;
    const int mb = blockIdx.x * TILE_M;
    const int k  = blockIdx.y;
    const int cg = blockIdx.z;
    const int cbase = cg * KC;

    float acc[4][4];
    #pragma unroll
    for (int j = 0; j < 4; ++j)
        #pragma unroll
        for (int i = 0; i < 4; ++i) acc[j][i] = 0.f;

    for (int c0 = 0; c0 < KC; c0 += CC) {
        for (int e = tid; e < TILE_M * (CC / 4); e += 256) {
            const int m = e / (CC / 4);
            const int c4 = (e % (CC / 4)) * 4;
            const float4 v = *(const float4*)&X[(size_t)(mb + m) * C + cbase + c0 + c4];
            Xs[c4 + 0][m] = v.x;
            Xs[c4 + 1][m] = v.y;
            Xs[c4 + 2][m] = v.z;
            Xs[c4 + 3][m] = v.w;
        }
        const float* wg = Wt + ((size_t)k * C + cbase + c0) * F;
        for (int t = tid; t < CC * F / 4; t += 256)
            ((float4*)Ws)[t] = ((const float4*)wg)[t];
        __syncthreads();
        #pragma unroll
        for (int cc = 0; cc < CC; ++cc) {
            const float4 xv = *(const float4*)&Xs[cc][m0];
            const float4 wv = *(const float4*)&Ws[cc][f0];
            acc[0][0] = fmaf(xv.x, wv.x, acc[0][0]);
            acc[0][1] = fmaf(xv.x, wv.y, acc[0][1]);
            acc[0][2] = fmaf(xv.x, wv.z, acc[0][2]);
            acc[0][3] = fmaf(xv.x, wv.w, acc[0][3]);
            acc[1][0] = fmaf(xv.y, wv.x, acc[1][0]);
            acc[1][1] = fmaf(xv.y, wv.y, acc[1][1]);
            acc[1][2] = fmaf(xv.y, wv.z, acc[1][2]);
            acc[1][3] = fmaf(xv.y, wv.w, acc[1][3]);
            acc[2][0] = fmaf(xv.z, wv.x, acc[2][0]);
            acc[2][1] = fmaf(xv.z, wv.y, acc[2][1]);
            acc[2][2] = fmaf(xv.z, wv.z, acc[2][2]);
            acc[2][3] = fmaf(xv.z, wv.w, acc[2][3]);
            acc[3][0] = fmaf(xv.w, wv.x, acc[3][0]);
            acc[3][1] = fmaf(xv.w, wv.y, acc[3][1]);
            acc[3][2] = fmaf(xv.w, wv.z, acc[3][2]);
            acc[3][3] = fmaf(xv.w, wv.w, acc[3][3]);
        }
        __syncthreads();
    }
    float* yb = Yout + ((size_t)(cg * K49 + k)) * M * F;
    #pragma unroll
    for (int j = 0; j < 4; ++j) {
        float4 o = make_float4(acc[j][0], acc[j][1], acc[j][2], acc[j][3]);
        *(float4*)&yb[(size_t)(mb + m0 + j) * F + f0] = o;
    }
}

// ============ sum KSPLIT partial Y slabs ============
__global__ __launch_bounds__(256) void k_reduceY(
    const float* __restrict__ partial, float* __restrict__ Y,
    const int n, const int G)
{
    const int gid = blockIdx.x * 256 + threadIdx.x;
    if (gid >= n) return;
    float a = 0.f;
    for (int g = 0; g < G; ++g) a += partial[(size_t)g * n + gid];
    Y[gid] = a;
}

// ============ combine: out[pix,f] = relu(b_f + sum_k s_k * Y[k][src_k*F+f]) =
template<int F>
__global__ __launch_bounds__(256) void k_combine(
    const float* __restrict__ Y,   // [49][nsrc*F]
    const float* __restrict__ SW, const int* __restrict__ SIDX,
    const float* __restrict__ bias, float* __restrict__ out,
    const int nsrc, const int do_relu)
{
    constexpr int PPB = 256 / F;
    const int tid = threadIdx.x;
    const int f = tid % F;
    const int pix = blockIdx.x * PPB + tid / F;
    const size_t strideY = (size_t)nsrc * F;
    float acc = bias[f];
    #pragma unroll 7
    for (int k = 0; k < K49; ++k) {
        const float s = SW[(size_t)pix * K49 + k];
        const int src = SIDX[(size_t)pix * K49 + k];
        acc = fmaf(s, Y[(size_t)k * strideY + (size_t)src * F + f], acc);
    }
    out[(size_t)pix * F + f] = do_relu ? fmaxf(acc, 0.f) : acc;
}

// ============ stage 4 Y: Y4[k][src] = X3[src,:16] . W4[k,:16] ============
__global__ __launch_bounds__(256) void k_y4(
    const float* __restrict__ X,   // [M,16]
    const float* __restrict__ Wt,  // [49,16]
    float* __restrict__ Y,         // [49][M]
    const int M)
{
    __shared__ float Ws[K49 * 16];
    const int tid = threadIdx.x;
    for (int t = tid; t < K49 * 16; t += 256) Ws[t] = Wt[t];
    __syncthreads();
    const int src = blockIdx.x * 256 + tid;
    const float4* xr = (const float4*)(X + (size_t)src * 16);
    const float4 a0 = xr[0], a1 = xr[1], a2 = xr[2], a3 = xr[3];
    for (int k = 0; k < K49; ++k) {
        const float* wr = Ws + k * 16;
        float d = a0.x*wr[0]  + a0.y*wr[1]  + a0.z*wr[2]  + a0.w*wr[3]
                + a1.x*wr[4]  + a1.y*wr[5]  + a1.z*wr[6]  + a1.w*wr[7]
                + a2.x*wr[8]  + a2.y*wr[9]  + a2.z*wr[10] + a2.w*wr[11]
                + a3.x*wr[12] + a3.y*wr[13] + a3.z*wr[14] + a3.w*wr[15];
        Y[(size_t)k * M + src] = d;
    }
}

// ============ stage 4: fused sparams + gather-combine via Y4, 4-lane split ===
__global__ __launch_bounds__(256) void k_dconv_f1_y(
    const float* __restrict__ Y4,       // [49][nsrc]
    const float* __restrict__ part,     // [npix, 98] raw offset conv (no bias)
    const float* __restrict__ OB,       // [98]
    const float* __restrict__ bias, float* __restrict__ out,
    const int H, const int W, const int Hp, const int Wp,
    const int pix0, const int nsrc)
{
    __shared__ float OBs[98];
    const int tid = threadIdx.x;
    if (tid < 98) OBs[tid] = OB[tid];
    __syncthreads();

    const int pixL = blockIdx.x * 64 + (tid >> 2);
    const int tq = tid & 3;
    const int t0 = (tq == 0) ? 0 : 13 + (tq - 1) * 12;
    const int t1 = t0 + ((tq == 0) ? 13 : 12);

    const int pixg = pix0 + pixL;
    const int HWp = Hp * Wp;
    const int b = pixg / HWp;
    const int rem = pixg - b * HWp;
    const int hp = rem / Wp;
    const int wp = rem - hp * Wp;

    float acc = 0.f;
    for (int k = t0; k < t1; ++k) {
        const float offy = part[(size_t)pixL * 98 + 2 * k]     + OBs[2 * k];
        const float offx = part[(size_t)pixL * 98 + 2 * k + 1] + OBs[2 * k + 1];
        const float y = (float)(hp + (k / 7) - 3) + offy;
        const float x = (float)(wp + (k % 7) - 3) + offx;
        const float fy0 = floorf(y), fx0 = floorf(x);
        const int iy0 = (int)fy0, ix0 = (int)fx0;
        const float wy1 = y - fy0, wx1 = x - fx0;
        int ye, xe; float wy, wx;
        if (iy0 & 1) { ye = iy0 + 1; wy = wy1; } else { ye = iy0; wy = 1.f - wy1; }
        if (ix0 & 1) { xe = ix0 + 1; wx = wx1; } else { xe = ix0; wx = 1.f - wx1; }
        float s = wy * wx;
        int src = 0;
        if (ye >= 0 && ye < Hp && xe >= 0 && xe < Wp)
            src = (b * H + (ye >> 1)) * W + (xe >> 1);
        else
            s = 0.f;
        acc = fmaf(s, Y4[(size_t)k * nsrc + src], acc);
    }
    acc += __shfl_xor(acc, 1);
    acc += __shfl_xor(acc, 2);
    if (tq == 0) out[pixg] = acc + bias[0];
}

extern "C" void kernel_launch(void* const* d_in, const int* in_sizes, int n_in,
                              void* d_out, int out_size, void* d_ws, size_t ws_size,
                              hipStream_t stream) {
    const float* z   = (const float*)d_in[0];
    const float* dw  = (const float*)d_in[1];
    const float* db  = (const float*)d_in[2];
    const float* ow1 = (const float*)d_in[3];
    const float* ob1 = (const float*)d_in[4];
    const float* w1  = (const float*)d_in[5];
    const float* b1  = (const float*)d_in[6];
    const float* ow2 = (const float*)d_in[7];
    const float* ob2 = (const float*)d_in[8];
    const float* w2  = (const float*)d_in[9];
    const float* b2  = (const float*)d_in[10];
    const float* ow3 = (const float*)d_in[11];
    const float* ob3 = (const float*)d_in[12];
    const float* w3  = (const float*)d_in[13];
    const float* b3  = (const float*)d_in[14];
    const float* ow4 = (const float*)d_in[15];
    const float* ob4 = (const float*)d_in[16];
    const float* w4  = (const float*)d_in[17];
    const float* b4  = (const float*)d_in[18];

    // workspace layout (floats): total 6,537,216 floats = 26.1 MB
    float* ws   = (float*)d_ws;
    float* x0   = ws;                      // 262144  [2,8,16,1024]
    float* x1   = x0 + 262144;             // 65536   [2,16,32,64]
    float* x2   = x1 + 65536;              // 131072  [2,32,64,32]
    float* x3   = x2 + 131072;             // 262144  [2,64,128,16]
    float* sw   = x3 + 262144;             // 802816  (16384 pix * 49)
    int*   sidx = (int*)(sw + 802816);     // 802816
    float* part = (float*)(sidx + 802816); // 3407872 (off-partials / Y-partials / Y2 / Y3)
    float* Ybuf = part + 3407872;          // 802816  (Y1: 49*256*64; Y4: 49*16384)

    float* out = (float*)d_out;

    // ---- dense + relu ----
    k_dense_relu<<<512, 256, 0, stream>>>(z, dw, db, x0);

    // ---- stage 1: x0 [2,8,16,1024] -> x1 [2,16,32,64] (nsrc=256, npix=1024) ----
    {
        const int H = 8, W = 16, Hp = 16, Wp = 32, npix = 1024, nsrc = 256, CG = 32;
        // jobs = 4 classes * (R/2=16 * W2=1) = 64 -> grid (64, 32)
        dim3 go(64, CG);
        k_offgemm3<1024, 32><<<go, 256, 0, stream>>>(x0, H, W, ow1, part, Hp, Wp, 0, npix);
        k_sparams<<<(npix * K49 + 255) / 256, 256, 0, stream>>>(part, ob1, sw, sidx, npix, CG, H, W, Hp, Wp, 0);
        dim3 gy(nsrc * 64 / 4096, K49, 4);
        k_ygemm<1024, 64, 4><<<gy, 256, 0, stream>>>(x0, w1, part, nsrc);
        const int nY = K49 * nsrc * 64;
        k_reduceY<<<(nY + 255) / 256, 256, 0, stream>>>(part, Ybuf, nY, 4);
        k_combine<64><<<npix * 64 / 256, 256, 0, stream>>>(Ybuf, sw, sidx, b1, x1, nsrc, 1);
    }

    // ---- stage 2: x1 [2,16,32,64] -> x2 [2,32,64,32] (nsrc=1024, npix=4096) ----
    {
        const int H = 16, W = 32, Hp = 32, Wp = 64, npix = 4096, nsrc = 1024, CG = 4;
        // jobs = 4 * (32 * 2) = 256 -> grid (256, 4)
        dim3 go(256, CG);
        k_offgemm3<64, 16><<<go, 256, 0, stream>>>(x1, H, W, ow2, part, Hp, Wp, 0, npix);
        k_sparams<<<(npix * K49 + 255) / 256, 256, 0, stream>>>(part, ob2, sw, sidx, npix, CG, H, W, Hp, Wp, 0);
        dim3 gy(nsrc * 32 / 4096, K49, 1);
        k_ygemm<64, 32, 1><<<gy, 256, 0, stream>>>(x1, w2, part, nsrc);   // Y2 lives in part
        k_combine<32><<<npix * 32 / 256, 256, 0, stream>>>(part, sw, sidx, b2, x2, nsrc, 1);
    }

    // ---- stage 3: x2 [2,32,64,32] -> x3 [2,64,128,16] (nsrc=4096, npix=16384) ----
    {
        const int H = 32, W = 64, Hp = 64, Wp = 128, npix = 16384, nsrc = 4096, CG = 1;
        // jobs = 4 * (64 * 4) = 1024 -> grid (1024, 1)
        dim3 go(1024, CG);
        k_offgemm3<32, 32><<<go, 256, 0, stream>>>(x2, H, W, ow3, part, Hp, Wp, 0, npix);
        k_sparams<<<(npix * K49 + 255) / 256, 256, 0, stream>>>(part, ob3, sw, sidx, npix, CG, H, W, Hp, Wp, 0);
        dim3 gy(nsrc * 16 / 4096, K49, 1);
        k_ygemm<32, 16, 1><<<gy, 256, 0, stream>>>(x2, w3, part, nsrc);   // Y3 lives in part
        k_combine<16><<<npix * 16 / 256, 256, 0, stream>>>(part, sw, sidx, b3, x3, nsrc, 1);
    }

    // ---- stage 4: x3 [2,64,128,16] -> out [2,128,256,1] (nsrc=16384), 2 chunks ----
    {
        const int H = 64, W = 128, Hp = 128, Wp = 256, CHUNK = 32768, nsrc = 16384;
        k_y4<<<nsrc / 256, 256, 0, stream>>>(x3, w4, Ybuf, nsrc);
        for (int c = 0; c < 2; ++c) {
            const int pix0 = c * CHUNK;
            // jobs = 4 * (64 * 8) = 2048 -> grid (2048, 1)
            dim3 go(2048, 1);
            k_offgemm3<16, 16><<<go, 256, 0, stream>>>(x3, H, W, ow4, part, Hp, Wp, pix0, CHUNK);
            k_dconv_f1_y<<<CHUNK / 64, 256, 0, stream>>>(Ybuf, part, ob4, b4, out, H, W, Hp, Wp, pix0, nsrc);
        }
    }
}